// Round 5
// baseline (556.491 us; speedup 1.0000x reference)
//
#include <hip/hip_runtime.h>

// Problem constants: B=4, S=2048, D=1024, H=16, HD=64
#define SEQ  2048
#define DIM  1024
#define NH   16
#define HD   64
#define NB   4

typedef __bf16 bf16_t;
typedef bf16_t bf16x8 __attribute__((ext_vector_type(8)));
typedef float  floatx4 __attribute__((ext_vector_type(4)));

#define MFMA16(a, b, c) __builtin_amdgcn_mfma_f32_16x16x32_bf16((a), (b), (c), 0, 0, 0)

// async global->LDS, 16B per lane (GEMM staging only; layout must be unpadded).
__device__ __forceinline__ void gl_lds16(const bf16_t* g, bf16_t* l) {
    __builtin_amdgcn_global_load_lds(
        (const __attribute__((address_space(1))) void*)g,
        (__attribute__((address_space(3))) void*)l,
        16, 0, 0);
}

// ---------------------------------------------------------------------------
// fp32 -> bf16 elementwise convert (n multiple of 1024)
// ---------------------------------------------------------------------------
__global__ __launch_bounds__(256) void cvt_f32_bf16(
    const float* __restrict__ in, bf16_t* __restrict__ out, int n) {
    const int i = (blockIdx.x * 256 + threadIdx.x) * 4;
    const float4 v = *(const float4*)(in + i);
    out[i + 0] = (bf16_t)v.x;
    out[i + 1] = (bf16_t)v.y;
    out[i + 2] = (bf16_t)v.z;
    out[i + 3] = (bf16_t)v.w;
}

// ---------------------------------------------------------------------------
// Transpose fp32 [R,C] -> bf16 [C,R]
// ---------------------------------------------------------------------------
__global__ __launch_bounds__(256) void transpose_f32_bf16(
    const float* __restrict__ in, bf16_t* __restrict__ out, int R, int C) {
    __shared__ bf16_t t[32][33];
    const int c0 = blockIdx.x * 32, r0 = blockIdx.y * 32;
    const int tx = threadIdx.x & 31, ty = threadIdx.x >> 5;  // 32 x 8
#pragma unroll
    for (int i = 0; i < 32; i += 8)
        t[ty + i][tx] = (bf16_t)in[(r0 + ty + i) * C + c0 + tx];
    __syncthreads();
#pragma unroll
    for (int i = 0; i < 32; i += 8)
        out[(c0 + ty + i) * R + r0 + tx] = t[tx][ty + i];
}

// ---------------------------------------------------------------------------
// GEMM: C[M,N] = A[M,K] * Bt[N,K]^T + bias[n]   (A,Bt bf16; bias fp32)
// MODE 0: LDS-staged epilogue -> coalesced 16B stores to
//         Q*0.125 [b,h,s,d], K[b,h,s,d], Vt[b,h,d,s]  (bf16)
// MODE 1: fp32 C row-major (N==1024), direct coalesced stores
// ---------------------------------------------------------------------------
template <int MODE>
__global__ __launch_bounds__(256, 2) void gemm128(
    const bf16_t* __restrict__ A, const bf16_t* __restrict__ Bt,
    const float* __restrict__ bias, int K,
    bf16_t* __restrict__ Qo, bf16_t* __restrict__ Ko, bf16_t* __restrict__ Vo,
    float* __restrict__ Co) {
    // staging: Al/Bl 128x32 each (16 KB); MODE 0 epilogue reuses as 128x136 C-tile
    __shared__ __align__(16) bf16_t smem[MODE == 0 ? 128 * 136 : 128 * 64];
    bf16_t* Al = smem;
    bf16_t* Bl = smem + 128 * 32;

    const int tid = threadIdx.x;
    const int m0 = blockIdx.y * 128, n0 = blockIdx.x * 128;
    const int w = tid >> 6, lane = tid & 63;
    const int l15 = lane & 15, quad = lane >> 4;
    const int wm = (w & 1) * 64, wn = (w >> 1) * 64;

    floatx4 acc[4][4] = {};

    const bf16_t* aptr = A + (m0 + (tid >> 2)) * K + (tid & 3) * 8;
    const bf16_t* bptr = Bt + (n0 + (tid >> 2)) * K + (tid & 3) * 8;
    bf16_t* al = Al + tid * 8;
    bf16_t* bl = Bl + tid * 8;

    for (int k0 = 0; k0 < K; k0 += 32) {
        gl_lds16(aptr, al);
        gl_lds16(aptr + 64 * K, al + 2048);
        gl_lds16(bptr, bl);
        gl_lds16(bptr + 64 * K, bl + 2048);
        aptr += 32;
        bptr += 32;
        __syncthreads();

        bf16x8 af[4], bfr[4];
#pragma unroll
        for (int i = 0; i < 4; i++)
            af[i] = *(const bf16x8*)&Al[(wm + i * 16 + l15) * 32 + quad * 8];
#pragma unroll
        for (int j = 0; j < 4; j++)
            bfr[j] = *(const bf16x8*)&Bl[(wn + j * 16 + l15) * 32 + quad * 8];
#pragma unroll
        for (int i = 0; i < 4; i++)
#pragma unroll
            for (int j = 0; j < 4; j++)
                acc[i][j] = MFMA16(af[i], bfr[j], acc[i][j]);
        __syncthreads();
    }

    if (MODE == 0) {
        // ---- stage C tile (bias + Q-scale applied) into LDS, stride 136 ----
        bf16_t* Cl = smem;
        const int which = n0 >> 10;  // 0=Q 1=K 2=V, block-uniform
        const float qs = (which == 0) ? 0.125f : 1.0f;
#pragma unroll
        for (int j = 0; j < 4; j++) {
            const int ncol = wn + j * 16 + l15;
            const float bv = bias[n0 + ncol];
#pragma unroll
            for (int i = 0; i < 4; i++)
#pragma unroll
                for (int r = 0; r < 4; r++) {
                    const int mrow = wm + i * 16 + quad * 4 + r;
                    Cl[mrow * 136 + ncol] = (bf16_t)((acc[i][j][r] + bv) * qs);
                }
        }
        __syncthreads();

        if (which < 2) {
            // rows are s; each head's 64 cols are contiguous d -> 16B stores
            const int row = tid >> 1, ch = (tid & 1) << 6;
            const int m = m0 + row, b = m >> 11, s = m & 2047;
            const int h = ((n0 & 1023) >> 6) + (ch >> 6);
            bf16_t* dst = (which == 0 ? Qo : Ko) + ((size_t)(b * NH + h) * SEQ + s) * HD;
            const bf16_t* src = Cl + row * 136 + ch;
#pragma unroll
            for (int g = 0; g < 8; g++)
                *(bf16x8*)(dst + g * 8) = *(const bf16x8*)(src + g * 8);
        } else {
            // V^T: read s-columns for fixed d, store contiguous s-runs
            const int dl = tid & 127, sh = (tid >> 7) << 6;
            const int h = ((n0 & 1023) >> 6) + (dl >> 6), d = dl & 63;
            const int b = m0 >> 11, sbase = (m0 & 2047) + sh;
            bf16_t* dst = Vo + ((size_t)(b * NH + h) * HD + d) * SEQ + sbase;
#pragma unroll
            for (int g = 0; g < 8; g++) {
                bf16x8 tv;
#pragma unroll
                for (int e = 0; e < 8; e++)
                    tv[e] = Cl[(sh + g * 8 + e) * 136 + dl];
                *(bf16x8*)(dst + g * 8) = tv;
            }
        }
    } else {
        // fp32 row-major, coalesced 4B stores
#pragma unroll
        for (int j = 0; j < 4; j++) {
            const int n = n0 + wn + j * 16 + l15;
            const float bv = bias[n];
#pragma unroll
            for (int i = 0; i < 4; i++)
#pragma unroll
                for (int r = 0; r < 4; r++) {
                    const int m = m0 + wm + i * 16 + quad * 4 + r;
                    Co[m * 1024 + n] = acc[i][j][r] + bv;
                }
        }
    }
}

// ---------------------------------------------------------------------------
// Flash attention, causal, no-running-max (scores bounded; masked -> exact 0).
// Block = 256 threads (4 waves), Q-tile 128 rows (wave w owns rows w*32..+31).
// K-tile 64 keys/iter. K/V in LDS with XOR-granule swizzle; P staged bf16
// [128][64] with XOR-granule swizzle (write ~2-way, read conflict-free b128).
// Q pre-scaled by 0.125. Row-sums reduced once in epilogue.
// ---------------------------------------------------------------------------
__global__ __launch_bounds__(256, 4) void attn128(
    const bf16_t* __restrict__ Q, const bf16_t* __restrict__ Kg,
    const bf16_t* __restrict__ Vt, bf16_t* __restrict__ Aout) {
    __shared__ bf16_t Ks[64 * 64];   // [key][d], granule-swizzled
    __shared__ bf16_t Vs[64 * 64];   // [d][key], granule-swizzled
    __shared__ bf16_t Ps[128 * 64];  // [qrow][key], granule-swizzled

    const int qt = 15 - blockIdx.x;  // longest blocks dispatch first
    const int bh = blockIdx.y;
    const int tid = threadIdx.x, w = tid >> 6, lane = tid & 63;
    const int l15 = lane & 15, quad = lane >> 4;
    const int b = bh >> 4, hd = bh & 15;

    // Q fragments (reused all iterations)
    bf16x8 aq[2][2];
#pragma unroll
    for (int i = 0; i < 2; i++) {
        const bf16_t* qr = Q + (size_t)(bh * SEQ + qt * 128 + w * 32 + i * 16 + l15) * HD;
#pragma unroll
        for (int h = 0; h < 2; h++)
            aq[i][h] = *(const bf16x8*)(qr + h * 32 + quad * 8);
    }

    floatx4 o[2][4] = {};
    float li[2][4] = {};

    // staging addressing: thread t -> tile row t>>2, granules (t&3), (t&3)+4
    const int r_st = tid >> 2, g0 = tid & 3;
    const bf16_t* kgl = Kg + (size_t)bh * SEQ * HD + (size_t)r_st * HD;
    const bf16_t* vgl = Vt + (size_t)bh * HD * SEQ + (size_t)r_st * SEQ;
    const int sw0 = ((g0 ^ (r_st & 7)) * 8);
    const int sw1 = (((g0 + 4) ^ (r_st & 7)) * 8);
    bf16_t* ksw = Ks + r_st * 64;
    bf16_t* vsw = Vs + r_st * 64;

    const int qrow0 = qt * 128 + w * 32;
    const int nk = 2 * qt + 2;
    const int xk = l15 & 7;

    for (int kt = 0; kt < nk; ++kt) {
        // ---- stage K/V tiles (swizzled) ----
        const bf16x8 k0 = *(const bf16x8*)(kgl + kt * 64 * HD + g0 * 8);
        const bf16x8 k1 = *(const bf16x8*)(kgl + kt * 64 * HD + (g0 + 4) * 8);
        const bf16x8 v0 = *(const bf16x8*)(vgl + kt * 64 + g0 * 8);
        const bf16x8 v1 = *(const bf16x8*)(vgl + kt * 64 + (g0 + 4) * 8);
        *(bf16x8*)(ksw + sw0) = k0;
        *(bf16x8*)(ksw + sw1) = k1;
        *(bf16x8*)(vsw + sw0) = v0;
        *(bf16x8*)(vsw + sw1) = v1;
        __syncthreads();

        // ---- S = Q K^T ----
        bf16x8 bk[4][2];
#pragma unroll
        for (int j = 0; j < 4; j++) {
            const int n = j * 16 + l15;
#pragma unroll
            for (int h = 0; h < 2; h++)
                bk[j][h] = *(const bf16x8*)&Ks[n * 64 + (((h * 4 + quad) ^ xk) * 8)];
        }
        floatx4 z[2][4] = {};
#pragma unroll
        for (int i = 0; i < 2; i++)
#pragma unroll
            for (int j = 0; j < 4; j++) {
                z[i][j] = MFMA16(aq[i][0], bk[j][0], z[i][j]);
                z[i][j] = MFMA16(aq[i][1], bk[j][1], z[i][j]);
            }

        // ---- exp (+ causal mask via select), row-sums, store P (bf16, swz) --
        const bool full = (kt * 64 + 63) <= qrow0;  // whole wave unmasked
#pragma unroll
        for (int i = 0; i < 2; i++)
#pragma unroll
            for (int j = 0; j < 4; j++) {
                const int kg = kt * 64 + j * 16 + l15;
#pragma unroll
                for (int r = 0; r < 4; r++) {
                    float e = __expf(z[i][j][r]);
                    const int prow = w * 32 + i * 16 + quad * 4 + r;
                    if (!full && kg > prow + qt * 128) e = 0.f;
                    li[i][r] += e;
                    const int col = j * 16 + l15;
                    Ps[prow * 64 + ((((col >> 3) ^ (prow & 7)) << 3) | (col & 7))] =
                        (bf16_t)e;
                }
            }
        __syncthreads();

        // ---- O += P V ----
        bf16x8 ap[2][2];
#pragma unroll
        for (int i = 0; i < 2; i++) {
            const int row = w * 32 + i * 16 + l15;
#pragma unroll
            for (int kk = 0; kk < 2; kk++)
                ap[i][kk] = *(const bf16x8*)&Ps[row * 64 +
                                               (((kk * 4 + quad) ^ (row & 7)) << 3)];
        }
        bf16x8 bv[4][2];
#pragma unroll
        for (int j = 0; j < 4; j++) {
            const int n = j * 16 + l15;
#pragma unroll
            for (int kk = 0; kk < 2; kk++)
                bv[j][kk] = *(const bf16x8*)&Vs[n * 64 + (((kk * 4 + quad) ^ xk) * 8)];
        }
#pragma unroll
        for (int i = 0; i < 2; i++)
#pragma unroll
            for (int j = 0; j < 4; j++) {
                o[i][j] = MFMA16(ap[i][0], bv[j][0], o[i][j]);
                o[i][j] = MFMA16(ap[i][1], bv[j][1], o[i][j]);
            }
        __syncthreads();
    }

    // ---- epilogue: reduce row-sums across the 16 col-lanes, normalize, store
#pragma unroll
    for (int i = 0; i < 2; i++)
#pragma unroll
        for (int r = 0; r < 4; r++) {
            float s = li[i][r];
#pragma unroll
            for (int off = 1; off < 16; off <<= 1)
                s += __shfl_xor(s, off, 64);
            const float inv = 1.0f / s;
            const int srow = qt * 128 + w * 32 + i * 16 + quad * 4 + r;
            bf16_t* orow = Aout + (size_t)(b * SEQ + srow) * DIM + hd * HD;
#pragma unroll
            for (int j = 0; j < 4; j++)
                orow[j * 16 + l15] = (bf16_t)(o[i][j][r] * inv);
        }
}

// ---------------------------------------------------------------------------
extern "C" void kernel_launch(void* const* d_in, const int* in_sizes, int n_in,
                              void* d_out, int out_size, void* d_ws, size_t ws_size,
                              hipStream_t stream) {
    const float* x        = (const float*)d_in[0];
    const float* c_attn_w = (const float*)d_in[2];
    const float* c_attn_b = (const float*)d_in[3];
    const float* c_proj_w = (const float*)d_in[4];
    const float* c_proj_b = (const float*)d_in[5];
    float* out = (float*)d_out;

    char* ws = (char*)d_ws;
    bf16_t* xb     = (bf16_t*)ws; ws += (size_t)NB * SEQ * DIM * 2;
    bf16_t* wqkvT  = (bf16_t*)ws; ws += (size_t)3072 * 1024 * 2;
    bf16_t* wprojT = (bf16_t*)ws; ws += (size_t)1024 * 1024 * 2;
    bf16_t* Qb  = (bf16_t*)ws; ws += (size_t)NB * NH * SEQ * HD * 2;
    bf16_t* Kb  = (bf16_t*)ws; ws += (size_t)NB * NH * SEQ * HD * 2;
    bf16_t* Vtb = (bf16_t*)ws; ws += (size_t)NB * NH * SEQ * HD * 2;
    bf16_t* Ab  = (bf16_t*)ws; ws += (size_t)NB * SEQ * DIM * 2;

    const int nx = NB * SEQ * DIM;  // 8388608
    cvt_f32_bf16<<<nx / 1024, 256, 0, stream>>>(x, xb, nx);
    transpose_f32_bf16<<<dim3(96, 32), 256, 0, stream>>>(c_attn_w, wqkvT, 1024, 3072);
    transpose_f32_bf16<<<dim3(32, 32), 256, 0, stream>>>(c_proj_w, wprojT, 1024, 1024);

    // qkv projection: M=8192, N=3072, K=1024
    gemm128<0><<<dim3(24, 64), 256, 0, stream>>>(xb, wqkvT, c_attn_b, 1024,
                                                 Qb, Kb, Vtb, nullptr);

    // attention: 16 q-tiles of 128 x 64 (b,h)
    attn128<<<dim3(16, NB * NH), 256, 0, stream>>>(Qb, Kb, Vtb, Ab);

    // output projection: M=8192, N=1024, K=1024, fp32 out
    gemm128<1><<<dim3(8, 64), 256, 0, stream>>>(Ab, wprojT, c_proj_b, 1024,
                                                nullptr, nullptr, nullptr, out);
}

// Round 6
// 343.247 us; speedup vs baseline: 1.6213x; 1.6213x over previous
//
#include <hip/hip_runtime.h>

// Problem constants: B=4, S=2048, D=1024, H=16, HD=64
#define SEQ  2048
#define DIM  1024
#define NH   16
#define HD   64
#define NB   4

typedef __bf16 bf16_t;
typedef bf16_t bf16x8 __attribute__((ext_vector_type(8)));
typedef float  floatx4 __attribute__((ext_vector_type(4)));

#define MFMA16(a, b, c) __builtin_amdgcn_mfma_f32_16x16x32_bf16((a), (b), (c), 0, 0, 0)

// async global->LDS, 16B per lane (GEMM staging only; layout must be unpadded).
__device__ __forceinline__ void gl_lds16(const bf16_t* g, bf16_t* l) {
    __builtin_amdgcn_global_load_lds(
        (const __attribute__((address_space(1))) void*)g,
        (__attribute__((address_space(3))) void*)l,
        16, 0, 0);
}

// ---------------------------------------------------------------------------
// fp32 -> bf16 elementwise convert (n multiple of 1024)
// ---------------------------------------------------------------------------
__global__ __launch_bounds__(256) void cvt_f32_bf16(
    const float* __restrict__ in, bf16_t* __restrict__ out, int n) {
    const int i = (blockIdx.x * 256 + threadIdx.x) * 4;
    const float4 v = *(const float4*)(in + i);
    out[i + 0] = (bf16_t)v.x;
    out[i + 1] = (bf16_t)v.y;
    out[i + 2] = (bf16_t)v.z;
    out[i + 3] = (bf16_t)v.w;
}

// ---------------------------------------------------------------------------
// Transpose fp32 [R,C] -> bf16 [C,R]
// ---------------------------------------------------------------------------
__global__ __launch_bounds__(256) void transpose_f32_bf16(
    const float* __restrict__ in, bf16_t* __restrict__ out, int R, int C) {
    __shared__ bf16_t t[32][33];
    const int c0 = blockIdx.x * 32, r0 = blockIdx.y * 32;
    const int tx = threadIdx.x & 31, ty = threadIdx.x >> 5;  // 32 x 8
#pragma unroll
    for (int i = 0; i < 32; i += 8)
        t[ty + i][tx] = (bf16_t)in[(r0 + ty + i) * C + c0 + tx];
    __syncthreads();
#pragma unroll
    for (int i = 0; i < 32; i += 8)
        out[(c0 + ty + i) * R + r0 + tx] = t[tx][ty + i];
}

// ---------------------------------------------------------------------------
// GEMM: C[M,N] = A[M,K] * Bt[N,K]^T + bias[n]   (A,Bt bf16; bias fp32)
// MODE 0: LDS-staged epilogue -> coalesced 16B stores to
//         Q*0.125 [b,h,s,d], K[b,h,s,d], Vt[b,h,d,s]  (bf16)
// MODE 1: fp32 C row-major (N==1024), direct coalesced stores
// ---------------------------------------------------------------------------
template <int MODE>
__global__ __launch_bounds__(256, 2) void gemm128(
    const bf16_t* __restrict__ A, const bf16_t* __restrict__ Bt,
    const float* __restrict__ bias, int K,
    bf16_t* __restrict__ Qo, bf16_t* __restrict__ Ko, bf16_t* __restrict__ Vo,
    float* __restrict__ Co) {
    // staging: Al/Bl 128x32 each (16 KB); MODE 0 epilogue reuses as 128x136 C-tile
    __shared__ __align__(16) bf16_t smem[MODE == 0 ? 128 * 136 : 128 * 64];
    bf16_t* Al = smem;
    bf16_t* Bl = smem + 128 * 32;

    const int tid = threadIdx.x;
    const int m0 = blockIdx.y * 128, n0 = blockIdx.x * 128;
    const int w = tid >> 6, lane = tid & 63;
    const int l15 = lane & 15, quad = lane >> 4;
    const int wm = (w & 1) * 64, wn = (w >> 1) * 64;

    floatx4 acc[4][4] = {};

    const bf16_t* aptr = A + (m0 + (tid >> 2)) * K + (tid & 3) * 8;
    const bf16_t* bptr = Bt + (n0 + (tid >> 2)) * K + (tid & 3) * 8;
    bf16_t* al = Al + tid * 8;
    bf16_t* bl = Bl + tid * 8;

    for (int k0 = 0; k0 < K; k0 += 32) {
        gl_lds16(aptr, al);
        gl_lds16(aptr + 64 * K, al + 2048);
        gl_lds16(bptr, bl);
        gl_lds16(bptr + 64 * K, bl + 2048);
        aptr += 32;
        bptr += 32;
        __syncthreads();

        bf16x8 af[4], bfr[4];
#pragma unroll
        for (int i = 0; i < 4; i++)
            af[i] = *(const bf16x8*)&Al[(wm + i * 16 + l15) * 32 + quad * 8];
#pragma unroll
        for (int j = 0; j < 4; j++)
            bfr[j] = *(const bf16x8*)&Bl[(wn + j * 16 + l15) * 32 + quad * 8];
#pragma unroll
        for (int i = 0; i < 4; i++)
#pragma unroll
            for (int j = 0; j < 4; j++)
                acc[i][j] = MFMA16(af[i], bfr[j], acc[i][j]);
        __syncthreads();
    }

    if (MODE == 0) {
        // ---- stage C tile (bias + Q-scale applied) into LDS, stride 136 ----
        bf16_t* Cl = smem;
        const int which = n0 >> 10;  // 0=Q 1=K 2=V, block-uniform
        const float qs = (which == 0) ? 0.125f : 1.0f;
#pragma unroll
        for (int j = 0; j < 4; j++) {
            const int ncol = wn + j * 16 + l15;
            const float bv = bias[n0 + ncol];
#pragma unroll
            for (int i = 0; i < 4; i++)
#pragma unroll
                for (int r = 0; r < 4; r++) {
                    const int mrow = wm + i * 16 + quad * 4 + r;
                    Cl[mrow * 136 + ncol] = (bf16_t)((acc[i][j][r] + bv) * qs);
                }
        }
        __syncthreads();

        if (which < 2) {
            // rows are s; each head's 64 cols are contiguous d -> 16B stores
            const int row = tid >> 1, ch = (tid & 1) << 6;
            const int m = m0 + row, b = m >> 11, s = m & 2047;
            const int h = ((n0 & 1023) >> 6) + (ch >> 6);
            bf16_t* dst = (which == 0 ? Qo : Ko) + ((size_t)(b * NH + h) * SEQ + s) * HD;
            const bf16_t* src = Cl + row * 136 + ch;
#pragma unroll
            for (int g = 0; g < 8; g++)
                *(bf16x8*)(dst + g * 8) = *(const bf16x8*)(src + g * 8);
        } else {
            // V^T: read s-columns for fixed d, store contiguous s-runs
            const int dl = tid & 127, sh = (tid >> 7) << 6;
            const int h = ((n0 & 1023) >> 6) + (dl >> 6), d = dl & 63;
            const int b = m0 >> 11, sbase = (m0 & 2047) + sh;
            bf16_t* dst = Vo + ((size_t)(b * NH + h) * HD + d) * SEQ + sbase;
#pragma unroll
            for (int g = 0; g < 8; g++) {
                bf16x8 tv;
#pragma unroll
                for (int e = 0; e < 8; e++)
                    tv[e] = Cl[(sh + g * 8 + e) * 136 + dl];
                *(bf16x8*)(dst + g * 8) = tv;
            }
        }
    } else {
        // fp32 row-major, coalesced 4B stores
#pragma unroll
        for (int j = 0; j < 4; j++) {
            const int n = n0 + wn + j * 16 + l15;
            const float bv = bias[n];
#pragma unroll
            for (int i = 0; i < 4; i++)
#pragma unroll
                for (int r = 0; r < 4; r++) {
                    const int m = m0 + wm + i * 16 + quad * 4 + r;
                    Co[m * 1024 + n] = acc[i][j][r] + bv;
                }
        }
    }
}

// ---------------------------------------------------------------------------
// Flash attention, causal, no-running-max (scores bounded; masked -> exact 0).
// Block = 256 threads (4 waves), Q-tile 128 rows (wave w owns rows w*32..+31).
// K-tile 64 keys/iter. K/V in LDS with XOR-granule swizzle; P staged bf16
// [128][64] with XOR-granule swizzle (write ~2-way, read conflict-free b128).
// Q pre-scaled by 0.125. Row-sums reduced once in epilogue.
// NOTE: min-waves/EU must stay <=3 — (256,4) forced VGPR 84->64 and spilled
// accumulators to scratch (FETCH 114->319 MB, 2.8x slower). Round-5 lesson.
// ---------------------------------------------------------------------------
__global__ __launch_bounds__(256, 3) void attn128(
    const bf16_t* __restrict__ Q, const bf16_t* __restrict__ Kg,
    const bf16_t* __restrict__ Vt, bf16_t* __restrict__ Aout) {
    __shared__ bf16_t Ks[64 * 64];   // [key][d], granule-swizzled
    __shared__ bf16_t Vs[64 * 64];   // [d][key], granule-swizzled
    __shared__ bf16_t Ps[128 * 64];  // [qrow][key], granule-swizzled

    const int qt = 15 - blockIdx.x;  // longest blocks dispatch first
    const int bh = blockIdx.y;
    const int tid = threadIdx.x, w = tid >> 6, lane = tid & 63;
    const int l15 = lane & 15, quad = lane >> 4;
    const int b = bh >> 4, hd = bh & 15;

    // Q fragments (reused all iterations)
    bf16x8 aq[2][2];
#pragma unroll
    for (int i = 0; i < 2; i++) {
        const bf16_t* qr = Q + (size_t)(bh * SEQ + qt * 128 + w * 32 + i * 16 + l15) * HD;
#pragma unroll
        for (int h = 0; h < 2; h++)
            aq[i][h] = *(const bf16x8*)(qr + h * 32 + quad * 8);
    }

    floatx4 o[2][4] = {};
    float li[2][4] = {};

    // staging addressing: thread t -> tile row t>>2, granules (t&3), (t&3)+4
    const int r_st = tid >> 2, g0 = tid & 3;
    const bf16_t* kgl = Kg + (size_t)bh * SEQ * HD + (size_t)r_st * HD;
    const bf16_t* vgl = Vt + (size_t)bh * HD * SEQ + (size_t)r_st * SEQ;
    const int sw0 = ((g0 ^ (r_st & 7)) * 8);
    const int sw1 = (((g0 + 4) ^ (r_st & 7)) * 8);
    bf16_t* ksw = Ks + r_st * 64;
    bf16_t* vsw = Vs + r_st * 64;

    const int qrow0 = qt * 128 + w * 32;
    const int nk = 2 * qt + 2;
    const int xk = l15 & 7;

    for (int kt = 0; kt < nk; ++kt) {
        // ---- stage K/V tiles (swizzled) ----
        const bf16x8 k0 = *(const bf16x8*)(kgl + kt * 64 * HD + g0 * 8);
        const bf16x8 k1 = *(const bf16x8*)(kgl + kt * 64 * HD + (g0 + 4) * 8);
        const bf16x8 v0 = *(const bf16x8*)(vgl + kt * 64 + g0 * 8);
        const bf16x8 v1 = *(const bf16x8*)(vgl + kt * 64 + (g0 + 4) * 8);
        *(bf16x8*)(ksw + sw0) = k0;
        *(bf16x8*)(ksw + sw1) = k1;
        *(bf16x8*)(vsw + sw0) = v0;
        *(bf16x8*)(vsw + sw1) = v1;
        __syncthreads();

        // ---- S = Q K^T ----
        bf16x8 bk[4][2];
#pragma unroll
        for (int j = 0; j < 4; j++) {
            const int n = j * 16 + l15;
#pragma unroll
            for (int h = 0; h < 2; h++)
                bk[j][h] = *(const bf16x8*)&Ks[n * 64 + (((h * 4 + quad) ^ xk) * 8)];
        }
        floatx4 z[2][4] = {};
#pragma unroll
        for (int i = 0; i < 2; i++)
#pragma unroll
            for (int j = 0; j < 4; j++) {
                z[i][j] = MFMA16(aq[i][0], bk[j][0], z[i][j]);
                z[i][j] = MFMA16(aq[i][1], bk[j][1], z[i][j]);
            }

        // ---- exp (+ causal mask via select), row-sums, store P (bf16, swz) --
        const bool full = (kt * 64 + 63) <= qrow0;  // whole wave unmasked
#pragma unroll
        for (int i = 0; i < 2; i++)
#pragma unroll
            for (int j = 0; j < 4; j++) {
                const int kg = kt * 64 + j * 16 + l15;
#pragma unroll
                for (int r = 0; r < 4; r++) {
                    float e = __expf(z[i][j][r]);
                    const int prow = w * 32 + i * 16 + quad * 4 + r;
                    if (!full && kg > prow + qt * 128) e = 0.f;
                    li[i][r] += e;
                    const int col = j * 16 + l15;
                    Ps[prow * 64 + ((((col >> 3) ^ (prow & 7)) << 3) | (col & 7))] =
                        (bf16_t)e;
                }
            }
        __syncthreads();

        // ---- O += P V ----
        bf16x8 ap[2][2];
#pragma unroll
        for (int i = 0; i < 2; i++) {
            const int row = w * 32 + i * 16 + l15;
#pragma unroll
            for (int kk = 0; kk < 2; kk++)
                ap[i][kk] = *(const bf16x8*)&Ps[row * 64 +
                                               (((kk * 4 + quad) ^ (row & 7)) << 3)];
        }
        bf16x8 bv[4][2];
#pragma unroll
        for (int j = 0; j < 4; j++) {
            const int n = j * 16 + l15;
#pragma unroll
            for (int kk = 0; kk < 2; kk++)
                bv[j][kk] = *(const bf16x8*)&Vs[n * 64 + (((kk * 4 + quad) ^ xk) * 8)];
        }
#pragma unroll
        for (int i = 0; i < 2; i++)
#pragma unroll
            for (int j = 0; j < 4; j++) {
                o[i][j] = MFMA16(ap[i][0], bv[j][0], o[i][j]);
                o[i][j] = MFMA16(ap[i][1], bv[j][1], o[i][j]);
            }
        __syncthreads();
    }

    // ---- epilogue: reduce row-sums across the 16 col-lanes, normalize, store
#pragma unroll
    for (int i = 0; i < 2; i++)
#pragma unroll
        for (int r = 0; r < 4; r++) {
            float s = li[i][r];
#pragma unroll
            for (int off = 1; off < 16; off <<= 1)
                s += __shfl_xor(s, off, 64);
            const float inv = 1.0f / s;
            const int srow = qt * 128 + w * 32 + i * 16 + quad * 4 + r;
            bf16_t* orow = Aout + (size_t)(b * SEQ + srow) * DIM + hd * HD;
#pragma unroll
            for (int j = 0; j < 4; j++)
                orow[j * 16 + l15] = (bf16_t)(o[i][j][r] * inv);
        }
}

// ---------------------------------------------------------------------------
extern "C" void kernel_launch(void* const* d_in, const int* in_sizes, int n_in,
                              void* d_out, int out_size, void* d_ws, size_t ws_size,
                              hipStream_t stream) {
    const float* x        = (const float*)d_in[0];
    const float* c_attn_w = (const float*)d_in[2];
    const float* c_attn_b = (const float*)d_in[3];
    const float* c_proj_w = (const float*)d_in[4];
    const float* c_proj_b = (const float*)d_in[5];
    float* out = (float*)d_out;

    char* ws = (char*)d_ws;
    bf16_t* xb     = (bf16_t*)ws; ws += (size_t)NB * SEQ * DIM * 2;
    bf16_t* wqkvT  = (bf16_t*)ws; ws += (size_t)3072 * 1024 * 2;
    bf16_t* wprojT = (bf16_t*)ws; ws += (size_t)1024 * 1024 * 2;
    bf16_t* Qb  = (bf16_t*)ws; ws += (size_t)NB * NH * SEQ * HD * 2;
    bf16_t* Kb  = (bf16_t*)ws; ws += (size_t)NB * NH * SEQ * HD * 2;
    bf16_t* Vtb = (bf16_t*)ws; ws += (size_t)NB * NH * SEQ * HD * 2;
    bf16_t* Ab  = (bf16_t*)ws; ws += (size_t)NB * SEQ * DIM * 2;

    const int nx = NB * SEQ * DIM;  // 8388608
    cvt_f32_bf16<<<nx / 1024, 256, 0, stream>>>(x, xb, nx);
    transpose_f32_bf16<<<dim3(96, 32), 256, 0, stream>>>(c_attn_w, wqkvT, 1024, 3072);
    transpose_f32_bf16<<<dim3(32, 32), 256, 0, stream>>>(c_proj_w, wprojT, 1024, 1024);

    // qkv projection: M=8192, N=3072, K=1024
    gemm128<0><<<dim3(24, 64), 256, 0, stream>>>(xb, wqkvT, c_attn_b, 1024,
                                                 Qb, Kb, Vtb, nullptr);

    // attention: 16 q-tiles of 128 x 64 (b,h)
    attn128<<<dim3(16, NB * NH), 256, 0, stream>>>(Qb, Kb, Vtb, Ab);

    // output projection: M=8192, N=1024, K=1024, fp32 out
    gemm128<1><<<dim3(8, 64), 256, 0, stream>>>(Ab, wprojT, c_proj_b, 1024,
                                                nullptr, nullptr, nullptr, out);
}

// Round 7
// 295.249 us; speedup vs baseline: 1.8848x; 1.1626x over previous
//
#include <hip/hip_runtime.h>

// Problem constants: B=4, S=2048, D=1024, H=16, HD=64
#define SEQ  2048
#define DIM  1024
#define NH   16
#define HD   64
#define NB   4

typedef __bf16 bf16_t;
typedef bf16_t bf16x8 __attribute__((ext_vector_type(8)));
typedef float  floatx4 __attribute__((ext_vector_type(4)));

#define MFMA16(a, b, c) __builtin_amdgcn_mfma_f32_16x16x32_bf16((a), (b), (c), 0, 0, 0)

// async global->LDS, 16B per lane (GEMM staging only; layout must be unpadded).
__device__ __forceinline__ void gl_lds16(const bf16_t* g, bf16_t* l) {
    __builtin_amdgcn_global_load_lds(
        (const __attribute__((address_space(1))) void*)g,
        (__attribute__((address_space(3))) void*)l,
        16, 0, 0);
}

// ---------------------------------------------------------------------------
// fp32 -> bf16 elementwise convert (n multiple of 1024)
// ---------------------------------------------------------------------------
__global__ __launch_bounds__(256) void cvt_f32_bf16(
    const float* __restrict__ in, bf16_t* __restrict__ out, int n) {
    const int i = (blockIdx.x * 256 + threadIdx.x) * 4;
    const float4 v = *(const float4*)(in + i);
    out[i + 0] = (bf16_t)v.x;
    out[i + 1] = (bf16_t)v.y;
    out[i + 2] = (bf16_t)v.z;
    out[i + 3] = (bf16_t)v.w;
}

// ---------------------------------------------------------------------------
// Transpose fp32 [R,C] -> bf16 [C,R]
// ---------------------------------------------------------------------------
__global__ __launch_bounds__(256) void transpose_f32_bf16(
    const float* __restrict__ in, bf16_t* __restrict__ out, int R, int C) {
    __shared__ bf16_t t[32][33];
    const int c0 = blockIdx.x * 32, r0 = blockIdx.y * 32;
    const int tx = threadIdx.x & 31, ty = threadIdx.x >> 5;  // 32 x 8
#pragma unroll
    for (int i = 0; i < 32; i += 8)
        t[ty + i][tx] = (bf16_t)in[(r0 + ty + i) * C + c0 + tx];
    __syncthreads();
#pragma unroll
    for (int i = 0; i < 32; i += 8)
        out[(c0 + ty + i) * R + r0 + tx] = t[tx][ty + i];
}

// ---------------------------------------------------------------------------
// GEMM: C[M,N] = A[M,K] * Bt[N,K]^T + bias[n]   (A,Bt bf16; bias fp32)
// MODE 0: LDS-staged epilogue -> coalesced 16B stores to
//         Q*0.125 [b,h,s,d], K[b,h,s,d], Vt[b,h,d,s]  (bf16)
// MODE 1: fp32 C row-major (N==1024), direct coalesced stores
// ---------------------------------------------------------------------------
template <int MODE>
__global__ __launch_bounds__(256, 2) void gemm128(
    const bf16_t* __restrict__ A, const bf16_t* __restrict__ Bt,
    const float* __restrict__ bias, int K,
    bf16_t* __restrict__ Qo, bf16_t* __restrict__ Ko, bf16_t* __restrict__ Vo,
    float* __restrict__ Co) {
    // staging: Al/Bl 128x32 each (16 KB); MODE 0 epilogue reuses as 128x136 C-tile
    __shared__ __align__(16) bf16_t smem[MODE == 0 ? 128 * 136 : 128 * 64];
    bf16_t* Al = smem;
    bf16_t* Bl = smem + 128 * 32;

    const int tid = threadIdx.x;
    const int m0 = blockIdx.y * 128, n0 = blockIdx.x * 128;
    const int w = tid >> 6, lane = tid & 63;
    const int l15 = lane & 15, quad = lane >> 4;
    const int wm = (w & 1) * 64, wn = (w >> 1) * 64;

    floatx4 acc[4][4] = {};

    const bf16_t* aptr = A + (m0 + (tid >> 2)) * K + (tid & 3) * 8;
    const bf16_t* bptr = Bt + (n0 + (tid >> 2)) * K + (tid & 3) * 8;
    bf16_t* al = Al + tid * 8;
    bf16_t* bl = Bl + tid * 8;

    for (int k0 = 0; k0 < K; k0 += 32) {
        gl_lds16(aptr, al);
        gl_lds16(aptr + 64 * K, al + 2048);
        gl_lds16(bptr, bl);
        gl_lds16(bptr + 64 * K, bl + 2048);
        aptr += 32;
        bptr += 32;
        __syncthreads();

        bf16x8 af[4], bfr[4];
#pragma unroll
        for (int i = 0; i < 4; i++)
            af[i] = *(const bf16x8*)&Al[(wm + i * 16 + l15) * 32 + quad * 8];
#pragma unroll
        for (int j = 0; j < 4; j++)
            bfr[j] = *(const bf16x8*)&Bl[(wn + j * 16 + l15) * 32 + quad * 8];
#pragma unroll
        for (int i = 0; i < 4; i++)
#pragma unroll
            for (int j = 0; j < 4; j++)
                acc[i][j] = MFMA16(af[i], bfr[j], acc[i][j]);
        __syncthreads();
    }

    if (MODE == 0) {
        // ---- stage C tile (bias + Q-scale applied) into LDS, stride 136 ----
        bf16_t* Cl = smem;
        const int which = n0 >> 10;  // 0=Q 1=K 2=V, block-uniform
        const float qs = (which == 0) ? 0.125f : 1.0f;
#pragma unroll
        for (int j = 0; j < 4; j++) {
            const int ncol = wn + j * 16 + l15;
            const float bv = bias[n0 + ncol];
#pragma unroll
            for (int i = 0; i < 4; i++)
#pragma unroll
                for (int r = 0; r < 4; r++) {
                    const int mrow = wm + i * 16 + quad * 4 + r;
                    Cl[mrow * 136 + ncol] = (bf16_t)((acc[i][j][r] + bv) * qs);
                }
        }
        __syncthreads();

        if (which < 2) {
            // rows are s; each head's 64 cols are contiguous d -> 16B stores
            const int row = tid >> 1, ch = (tid & 1) << 6;
            const int m = m0 + row, b = m >> 11, s = m & 2047;
            const int h = ((n0 & 1023) >> 6) + (ch >> 6);
            bf16_t* dst = (which == 0 ? Qo : Ko) + ((size_t)(b * NH + h) * SEQ + s) * HD;
            const bf16_t* src = Cl + row * 136 + ch;
#pragma unroll
            for (int g = 0; g < 8; g++)
                *(bf16x8*)(dst + g * 8) = *(const bf16x8*)(src + g * 8);
        } else {
            // V^T: read s-columns for fixed d, store contiguous s-runs
            const int dl = tid & 127, sh = (tid >> 7) << 6;
            const int h = ((n0 & 1023) >> 6) + (dl >> 6), d = dl & 63;
            const int b = m0 >> 11, sbase = (m0 & 2047) + sh;
            bf16_t* dst = Vo + ((size_t)(b * NH + h) * HD + d) * SEQ + sbase;
#pragma unroll
            for (int g = 0; g < 8; g++) {
                bf16x8 tv;
#pragma unroll
                for (int e = 0; e < 8; e++)
                    tv[e] = Cl[(sh + g * 8 + e) * 136 + dl];
                *(bf16x8*)(dst + g * 8) = tv;
            }
        }
    } else {
        // fp32 row-major, coalesced 4B stores
#pragma unroll
        for (int j = 0; j < 4; j++) {
            const int n = n0 + wn + j * 16 + l15;
            const float bv = bias[n];
#pragma unroll
            for (int i = 0; i < 4; i++)
#pragma unroll
                for (int r = 0; r < 4; r++) {
                    const int m = m0 + wm + i * 16 + quad * 4 + r;
                    Co[m * 1024 + n] = acc[i][j][r] + bv;
                }
        }
    }
}

// ---------------------------------------------------------------------------
// Flash attention, causal, no-running-max. Two q-tiles per block:
// qtA = 15-px (long), qtB = px (short); shared kt loop stages each K/V tile
// ONCE and both tiles consume it (B only while kt < nkB). Every block does
// exactly 34 tile-computes -> perfectly balanced, grid 8x64 = 2 blocks/CU,
// all resident. Ps is wave-private (writer==reader): no barrier, just
// s_waitcnt lgkmcnt(0) (DS ops of one wave execute in order).
// NOTE round-5 lesson: never force occupancy that drops VGPR below need —
// (256,2) caps at 256 VGPR, no spill, and 2 blocks/CU is full residency.
// ---------------------------------------------------------------------------
__global__ __launch_bounds__(256, 2) void attn2q(
    const bf16_t* __restrict__ Q, const bf16_t* __restrict__ Kg,
    const bf16_t* __restrict__ Vt, bf16_t* __restrict__ Aout) {
    __shared__ bf16_t Ks[64 * 64];   // [key][d], granule-swizzled
    __shared__ bf16_t Vs[64 * 64];   // [d][key], granule-swizzled
    __shared__ bf16_t Ps[128 * 64];  // [qrow][key], granule-swizzled

    const int bh = blockIdx.y;
    const int px = (blockIdx.x + (bh >> 3)) & 7;  // scramble so CU-mates differ
    const int qtA = 15 - px, qtB = px;
    const int nkA = 2 * qtA + 2, nkB = 2 * qtB + 2;  // nkB <= 16 < 18 <= nkA

    const int tid = threadIdx.x, w = tid >> 6, lane = tid & 63;
    const int l15 = lane & 15, quad = lane >> 4;
    const int b = bh >> 4, hd = bh & 15;
    const int xk = l15 & 7;

    // Q fragments for both tiles (reused all iterations)
    bf16x8 aqA[2][2], aqB[2][2];
#pragma unroll
    for (int i = 0; i < 2; i++) {
        const bf16_t* qrA = Q + (size_t)(bh * SEQ + qtA * 128 + w * 32 + i * 16 + l15) * HD;
        const bf16_t* qrB = Q + (size_t)(bh * SEQ + qtB * 128 + w * 32 + i * 16 + l15) * HD;
#pragma unroll
        for (int h = 0; h < 2; h++) {
            aqA[i][h] = *(const bf16x8*)(qrA + h * 32 + quad * 8);
            aqB[i][h] = *(const bf16x8*)(qrB + h * 32 + quad * 8);
        }
    }

    floatx4 oA[2][4] = {}, oB[2][4] = {};
    float liA[2][4] = {}, liB[2][4] = {};

    // staging addressing: thread t -> tile row t>>2, granules (t&3), (t&3)+4
    const int r_st = tid >> 2, g0 = tid & 3;
    const bf16_t* kgl = Kg + (size_t)bh * SEQ * HD + (size_t)r_st * HD;
    const bf16_t* vgl = Vt + (size_t)bh * HD * SEQ + (size_t)r_st * SEQ;
    const int sw0 = ((g0 ^ (r_st & 7)) * 8);
    const int sw1 = (((g0 + 4) ^ (r_st & 7)) * 8);
    bf16_t* ksw = Ks + r_st * 64;
    bf16_t* vsw = Vs + r_st * 64;

    // one q-tile's compute against the currently staged K/V tile
    auto proc = [&](int qt, bf16x8 (&aq)[2][2], floatx4 (&o)[2][4],
                    float (&li)[2][4], int kt) {
        const int qrow0 = qt * 128 + w * 32;
        // S = Q K^T
        bf16x8 bk[4][2];
#pragma unroll
        for (int j = 0; j < 4; j++) {
            const int n = j * 16 + l15;
#pragma unroll
            for (int h = 0; h < 2; h++)
                bk[j][h] = *(const bf16x8*)&Ks[n * 64 + (((h * 4 + quad) ^ xk) * 8)];
        }
        floatx4 z[2][4] = {};
#pragma unroll
        for (int i = 0; i < 2; i++)
#pragma unroll
            for (int j = 0; j < 4; j++) {
                z[i][j] = MFMA16(aq[i][0], bk[j][0], z[i][j]);
                z[i][j] = MFMA16(aq[i][1], bk[j][1], z[i][j]);
            }
        // exp (+ causal mask), row-sums, store P (bf16, swizzled, wave-private)
        const bool full = (kt * 64 + 63) <= qrow0;
#pragma unroll
        for (int i = 0; i < 2; i++)
#pragma unroll
            for (int j = 0; j < 4; j++) {
                const int kg = kt * 64 + j * 16 + l15;
#pragma unroll
                for (int r = 0; r < 4; r++) {
                    float e = __expf(z[i][j][r]);
                    const int prow = w * 32 + i * 16 + quad * 4 + r;
                    if (!full && kg > prow + qt * 128) e = 0.f;
                    li[i][r] += e;
                    const int col = j * 16 + l15;
                    Ps[prow * 64 + ((((col >> 3) ^ (prow & 7)) << 3) | (col & 7))] =
                        (bf16_t)e;
                }
            }
        // wave-private Ps: wait own DS writes, no block barrier needed
        __builtin_amdgcn_s_waitcnt(0xC07F);  // lgkmcnt(0), vm/exp untouched
        // O += P V
        bf16x8 ap[2][2];
#pragma unroll
        for (int i = 0; i < 2; i++) {
            const int row = w * 32 + i * 16 + l15;
#pragma unroll
            for (int kk = 0; kk < 2; kk++)
                ap[i][kk] = *(const bf16x8*)&Ps[row * 64 +
                                               (((kk * 4 + quad) ^ (row & 7)) << 3)];
        }
        bf16x8 bv[4][2];
#pragma unroll
        for (int j = 0; j < 4; j++) {
            const int n = j * 16 + l15;
#pragma unroll
            for (int kk = 0; kk < 2; kk++)
                bv[j][kk] = *(const bf16x8*)&Vs[n * 64 + (((kk * 4 + quad) ^ xk) * 8)];
        }
#pragma unroll
        for (int i = 0; i < 2; i++)
#pragma unroll
            for (int j = 0; j < 4; j++) {
                o[i][j] = MFMA16(ap[i][0], bv[j][0], o[i][j]);
                o[i][j] = MFMA16(ap[i][1], bv[j][1], o[i][j]);
            }
    };

    for (int kt = 0; kt < nkA; ++kt) {
        // ---- stage K/V tile kt once (swizzled), consumed by both q-tiles ----
        const bf16x8 k0 = *(const bf16x8*)(kgl + kt * 64 * HD + g0 * 8);
        const bf16x8 k1 = *(const bf16x8*)(kgl + kt * 64 * HD + (g0 + 4) * 8);
        const bf16x8 v0 = *(const bf16x8*)(vgl + kt * 64 + g0 * 8);
        const bf16x8 v1 = *(const bf16x8*)(vgl + kt * 64 + (g0 + 4) * 8);
        *(bf16x8*)(ksw + sw0) = k0;
        *(bf16x8*)(ksw + sw1) = k1;
        *(bf16x8*)(vsw + sw0) = v0;
        *(bf16x8*)(vsw + sw1) = v1;
        __syncthreads();

        proc(qtA, aqA, oA, liA, kt);
        if (kt < nkB) proc(qtB, aqB, oB, liB, kt);
        __syncthreads();
    }

    // ---- epilogue: reduce row-sums, normalize, store both tiles ----
#pragma unroll
    for (int t = 0; t < 2; t++) {
        const int qt = t == 0 ? qtA : qtB;
        floatx4(&o)[2][4] = t == 0 ? oA : oB;
        float(&li)[2][4] = t == 0 ? liA : liB;
#pragma unroll
        for (int i = 0; i < 2; i++)
#pragma unroll
            for (int r = 0; r < 4; r++) {
                float s = li[i][r];
#pragma unroll
                for (int off = 1; off < 16; off <<= 1)
                    s += __shfl_xor(s, off, 64);
                const float inv = 1.0f / s;
                const int srow = qt * 128 + w * 32 + i * 16 + quad * 4 + r;
                bf16_t* orow = Aout + (size_t)(b * SEQ + srow) * DIM + hd * HD;
#pragma unroll
                for (int j = 0; j < 4; j++)
                    orow[j * 16 + l15] = (bf16_t)(o[i][j][r] * inv);
            }
    }
}

// ---------------------------------------------------------------------------
extern "C" void kernel_launch(void* const* d_in, const int* in_sizes, int n_in,
                              void* d_out, int out_size, void* d_ws, size_t ws_size,
                              hipStream_t stream) {
    const float* x        = (const float*)d_in[0];
    const float* c_attn_w = (const float*)d_in[2];
    const float* c_attn_b = (const float*)d_in[3];
    const float* c_proj_w = (const float*)d_in[4];
    const float* c_proj_b = (const float*)d_in[5];
    float* out = (float*)d_out;

    char* ws = (char*)d_ws;
    bf16_t* xb     = (bf16_t*)ws; ws += (size_t)NB * SEQ * DIM * 2;
    bf16_t* wqkvT  = (bf16_t*)ws; ws += (size_t)3072 * 1024 * 2;
    bf16_t* wprojT = (bf16_t*)ws; ws += (size_t)1024 * 1024 * 2;
    bf16_t* Qb  = (bf16_t*)ws; ws += (size_t)NB * NH * SEQ * HD * 2;
    bf16_t* Kb  = (bf16_t*)ws; ws += (size_t)NB * NH * SEQ * HD * 2;
    bf16_t* Vtb = (bf16_t*)ws; ws += (size_t)NB * NH * SEQ * HD * 2;
    bf16_t* Ab  = (bf16_t*)ws; ws += (size_t)NB * SEQ * DIM * 2;

    const int nx = NB * SEQ * DIM;  // 8388608
    cvt_f32_bf16<<<nx / 1024, 256, 0, stream>>>(x, xb, nx);
    transpose_f32_bf16<<<dim3(96, 32), 256, 0, stream>>>(c_attn_w, wqkvT, 1024, 3072);
    transpose_f32_bf16<<<dim3(32, 32), 256, 0, stream>>>(c_proj_w, wprojT, 1024, 1024);

    // qkv projection: M=8192, N=3072, K=1024
    gemm128<0><<<dim3(24, 64), 256, 0, stream>>>(xb, wqkvT, c_attn_b, 1024,
                                                 Qb, Kb, Vtb, nullptr);

    // attention: 8 paired q-tile blocks x 64 (b,h) — balanced, all resident
    attn2q<<<dim3(8, NB * NH), 256, 0, stream>>>(Qb, Kb, Vtb, Ab);

    // output projection: M=8192, N=1024, K=1024, fp32 out
    gemm128<1><<<dim3(8, 64), 256, 0, stream>>>(Ab, wprojT, c_proj_b, 1024,
                                                nullptr, nullptr, nullptr, out);
}

// Round 8
// 278.736 us; speedup vs baseline: 1.9965x; 1.0592x over previous
//
#include <hip/hip_runtime.h>

// Problem constants: B=4, S=2048, D=1024, H=16, HD=64
#define SEQ  2048
#define DIM  1024
#define NH   16
#define HD   64
#define NB   4

typedef __bf16 bf16_t;
typedef bf16_t bf16x8 __attribute__((ext_vector_type(8)));
typedef bf16_t bf16x4 __attribute__((ext_vector_type(4)));
typedef float  floatx4 __attribute__((ext_vector_type(4)));

#define MFMA16(a, b, c) __builtin_amdgcn_mfma_f32_16x16x32_bf16((a), (b), (c), 0, 0, 0)

// async global->LDS, 16B per lane (GEMM staging only; layout must be unpadded).
__device__ __forceinline__ void gl_lds16(const bf16_t* g, bf16_t* l) {
    __builtin_amdgcn_global_load_lds(
        (const __attribute__((address_space(1))) void*)g,
        (__attribute__((address_space(3))) void*)l,
        16, 0, 0);
}

// ---------------------------------------------------------------------------
// prep: fused fp32->bf16 convert of x + both weight transposes (one launch)
//   blocks [0, 8192)          : cvt x (8192*1024 elements)
//   blocks [8192, 8192+3072)  : transpose c_attn_w 1024x3072 -> 3072x1024
//   blocks [11264, 12288)     : transpose c_proj_w 1024x1024 -> 1024x1024
// ---------------------------------------------------------------------------
__global__ __launch_bounds__(256) void prep(
    const float* __restrict__ x, bf16_t* __restrict__ xb,
    const float* __restrict__ wqkv, bf16_t* __restrict__ wqkvT,
    const float* __restrict__ wproj, bf16_t* __restrict__ wprojT) {
    const int bid = blockIdx.x, tid = threadIdx.x;
    if (bid < 8192) {
        const int i = (bid * 256 + tid) * 4;
        const float4 v = *(const float4*)(x + i);
        xb[i + 0] = (bf16_t)v.x;
        xb[i + 1] = (bf16_t)v.y;
        xb[i + 2] = (bf16_t)v.z;
        xb[i + 3] = (bf16_t)v.w;
        return;
    }
    __shared__ bf16_t t[32][33];
    const float* in;
    bf16_t* out;
    int R, C, bx, by;
    if (bid < 8192 + 3072) {
        const int idx = bid - 8192;
        in = wqkv; out = wqkvT; R = 1024; C = 3072;
        bx = idx % 96; by = idx / 96;
    } else {
        const int idx = bid - 11264;
        in = wproj; out = wprojT; R = 1024; C = 1024;
        bx = idx & 31; by = idx >> 5;
    }
    const int c0 = bx * 32, r0 = by * 32;
    const int tx = tid & 31, ty = tid >> 5;  // 32 x 8
#pragma unroll
    for (int i = 0; i < 32; i += 8)
        t[ty + i][tx] = (bf16_t)in[(r0 + ty + i) * C + c0 + tx];
    __syncthreads();
#pragma unroll
    for (int i = 0; i < 32; i += 8)
        out[(c0 + ty + i) * R + r0 + tx] = t[tx][ty + i];
}

// ---------------------------------------------------------------------------
// GEMM: C[M,N] = A[M,K] * Bt[N,K]^T + bias[n]   (A,Bt bf16; bias fp32)
// MODE 0: LDS-staged epilogue -> coalesced 16B stores to
//         Q*0.125 [b,h,s,d], K[b,h,s,d], Vt[b,h,d,s]  (bf16)
// MODE 1: fp32 C row-major (N==1024), direct coalesced stores
// ---------------------------------------------------------------------------
template <int MODE>
__global__ __launch_bounds__(256, 2) void gemm128(
    const bf16_t* __restrict__ A, const bf16_t* __restrict__ Bt,
    const float* __restrict__ bias, int K,
    bf16_t* __restrict__ Qo, bf16_t* __restrict__ Ko, bf16_t* __restrict__ Vo,
    float* __restrict__ Co) {
    __shared__ __align__(16) bf16_t smem[MODE == 0 ? 128 * 136 : 128 * 64];
    bf16_t* Al = smem;
    bf16_t* Bl = smem + 128 * 32;

    const int tid = threadIdx.x;
    const int m0 = blockIdx.y * 128, n0 = blockIdx.x * 128;
    const int w = tid >> 6, lane = tid & 63;
    const int l15 = lane & 15, quad = lane >> 4;
    const int wm = (w & 1) * 64, wn = (w >> 1) * 64;

    floatx4 acc[4][4] = {};

    const bf16_t* aptr = A + (m0 + (tid >> 2)) * K + (tid & 3) * 8;
    const bf16_t* bptr = Bt + (n0 + (tid >> 2)) * K + (tid & 3) * 8;
    bf16_t* al = Al + tid * 8;
    bf16_t* bl = Bl + tid * 8;

    for (int k0 = 0; k0 < K; k0 += 32) {
        gl_lds16(aptr, al);
        gl_lds16(aptr + 64 * K, al + 2048);
        gl_lds16(bptr, bl);
        gl_lds16(bptr + 64 * K, bl + 2048);
        aptr += 32;
        bptr += 32;
        __syncthreads();

        bf16x8 af[4], bfr[4];
#pragma unroll
        for (int i = 0; i < 4; i++)
            af[i] = *(const bf16x8*)&Al[(wm + i * 16 + l15) * 32 + quad * 8];
#pragma unroll
        for (int j = 0; j < 4; j++)
            bfr[j] = *(const bf16x8*)&Bl[(wn + j * 16 + l15) * 32 + quad * 8];
#pragma unroll
        for (int i = 0; i < 4; i++)
#pragma unroll
            for (int j = 0; j < 4; j++)
                acc[i][j] = MFMA16(af[i], bfr[j], acc[i][j]);
        __syncthreads();
    }

    if (MODE == 0) {
        bf16_t* Cl = smem;
        const int which = n0 >> 10;  // 0=Q 1=K 2=V, block-uniform
        const float qs = (which == 0) ? 0.125f : 1.0f;
#pragma unroll
        for (int j = 0; j < 4; j++) {
            const int ncol = wn + j * 16 + l15;
            const float bv = bias[n0 + ncol];
#pragma unroll
            for (int i = 0; i < 4; i++)
#pragma unroll
                for (int r = 0; r < 4; r++) {
                    const int mrow = wm + i * 16 + quad * 4 + r;
                    Cl[mrow * 136 + ncol] = (bf16_t)((acc[i][j][r] + bv) * qs);
                }
        }
        __syncthreads();

        if (which < 2) {
            const int row = tid >> 1, ch = (tid & 1) << 6;
            const int m = m0 + row, b = m >> 11, s = m & 2047;
            const int h = ((n0 & 1023) >> 6) + (ch >> 6);
            bf16_t* dst = (which == 0 ? Qo : Ko) + ((size_t)(b * NH + h) * SEQ + s) * HD;
            const bf16_t* src = Cl + row * 136 + ch;
#pragma unroll
            for (int g = 0; g < 8; g++)
                *(bf16x8*)(dst + g * 8) = *(const bf16x8*)(src + g * 8);
        } else {
            const int dl = tid & 127, sh = (tid >> 7) << 6;
            const int h = ((n0 & 1023) >> 6) + (dl >> 6), d = dl & 63;
            const int b = m0 >> 11, sbase = (m0 & 2047) + sh;
            bf16_t* dst = Vo + ((size_t)(b * NH + h) * HD + d) * SEQ + sbase;
#pragma unroll
            for (int g = 0; g < 8; g++) {
                bf16x8 tv;
#pragma unroll
                for (int e = 0; e < 8; e++)
                    tv[e] = Cl[(sh + g * 8 + e) * 136 + dl];
                *(bf16x8*)(dst + g * 8) = tv;
            }
        }
    } else {
#pragma unroll
        for (int j = 0; j < 4; j++) {
            const int n = n0 + wn + j * 16 + l15;
            const float bv = bias[n];
#pragma unroll
            for (int i = 0; i < 4; i++)
#pragma unroll
                for (int r = 0; r < 4; r++) {
                    const int m = m0 + wm + i * 16 + quad * 4 + r;
                    Co[m * 1024 + n] = acc[i][j][r] + bv;
                }
        }
    }
}

// ---------------------------------------------------------------------------
// Flash attention, causal, no-running-max. Two q-tiles/block (qtA=15-px long,
// qtB=px short) share each staged K/V tile; 128 keys staged per barrier pair
// (two 64-key subtiles) -> barriers halved. S^T = K*Q^T so P exits MFMA with
// consecutive KEYS per lane -> packed b64 P-stores (8/proc vs 32 b16) and
// scalar per-lane row-sums. Ps wave-private: lgkmcnt(0) wait, no barrier.
// Round-5 lesson: never force occupancy below VGPR need — (256,2) only.
// ---------------------------------------------------------------------------
__global__ __launch_bounds__(256, 2) void attn2q(
    const bf16_t* __restrict__ Q, const bf16_t* __restrict__ Kg,
    const bf16_t* __restrict__ Vt, bf16_t* __restrict__ Aout) {
    __shared__ bf16_t Ks[2 * 64 * 64];  // [sub][key][d], granule-swizzled
    __shared__ bf16_t Vs[2 * 64 * 64];  // [sub][d][key], granule-swizzled
    __shared__ bf16_t Ps[128 * 64];     // [qrow][key],   granule-swizzled

    const int bh = blockIdx.y;
    const int px = (blockIdx.x + (bh >> 3)) & 7;  // scramble so CU-mates differ
    const int qtA = 15 - px, qtB = px;
    const int nkA = 2 * qtA + 2, nkB = 2 * qtB + 2;  // both even

    const int tid = threadIdx.x, w = tid >> 6, lane = tid & 63;
    const int l15 = lane & 15, quad = lane >> 4;
    const int b = bh >> 4, hd = bh & 15;
    const int xk = l15 & 7;

    // Q fragments for both tiles (B-operand of S^T = K Q^T)
    bf16x8 aqA[2][2], aqB[2][2];
#pragma unroll
    for (int i = 0; i < 2; i++) {
        const bf16_t* qrA = Q + (size_t)(bh * SEQ + qtA * 128 + w * 32 + i * 16 + l15) * HD;
        const bf16_t* qrB = Q + (size_t)(bh * SEQ + qtB * 128 + w * 32 + i * 16 + l15) * HD;
#pragma unroll
        for (int h = 0; h < 2; h++) {
            aqA[i][h] = *(const bf16x8*)(qrA + h * 32 + quad * 8);
            aqB[i][h] = *(const bf16x8*)(qrB + h * 32 + quad * 8);
        }
    }

    floatx4 oA[2][4] = {}, oB[2][4] = {};
    float liA[2] = {}, liB[2] = {};

    // staging: thread t -> subtile row t>>2, granules (t&3), (t&3)+4
    const int r_st = tid >> 2, g0 = tid & 3;
    const bf16_t* kgl = Kg + (size_t)bh * SEQ * HD + (size_t)r_st * HD;
    const bf16_t* vgl = Vt + (size_t)bh * HD * SEQ + (size_t)r_st * SEQ;
    const int sw0 = ((g0 ^ (r_st & 7)) * 8);
    const int sw1 = (((g0 + 4) ^ (r_st & 7)) * 8);

    auto proc = [&](int qt, bf16x8 (&aq)[2][2], floatx4 (&o)[2][4],
                    float (&li)[2], int kt, int sub) {
        const bf16_t* Ksub = Ks + sub * 4096;
        const bf16_t* Vsub = Vs + sub * 4096;
        // S^T = K Q^T : C col = qrow (l15), row = key (quad*4+r)
        bf16x8 bk[4][2];
#pragma unroll
        for (int j = 0; j < 4; j++) {
            const int n = j * 16 + l15;
#pragma unroll
            for (int h = 0; h < 2; h++)
                bk[j][h] = *(const bf16x8*)&Ksub[n * 64 + (((h * 4 + quad) ^ xk) * 8)];
        }
        floatx4 z[2][4] = {};
#pragma unroll
        for (int i = 0; i < 2; i++)
#pragma unroll
            for (int j = 0; j < 4; j++) {
                z[i][j] = MFMA16(bk[j][0], aq[i][0], z[i][j]);
                z[i][j] = MFMA16(bk[j][1], aq[i][1], z[i][j]);
            }
        // exp + causal mask + per-lane row-sum + packed b64 P-store
#pragma unroll
        for (int i = 0; i < 2; i++) {
            const int qbase = qt * 128 + w * 32 + i * 16;
            const int qrow_l = qbase + l15;
            const bool full = (kt * 64 + 63) <= qbase;
            const int prow = w * 32 + i * 16 + l15;
            bf16_t* pbase = Ps + prow * 64;
            const int rx = prow & 7;
#pragma unroll
            for (int j = 0; j < 4; j++) {
                const int kg0 = kt * 64 + j * 16 + quad * 4;
                bf16x4 pk;
#pragma unroll
                for (int r = 0; r < 4; r++) {
                    float e = __expf(z[i][j][r]);
                    if (!full && kg0 + r > qrow_l) e = 0.f;
                    li[i] += e;
                    pk[r] = (bf16_t)e;
                }
                const int g = 2 * j + (quad >> 1);
                *(bf16x4*)(pbase + (((g ^ rx) << 3) | ((quad & 1) << 2))) = pk;
            }
        }
        __builtin_amdgcn_s_waitcnt(0xC07F);  // lgkmcnt(0); Ps is wave-private
        // O += P V
        bf16x8 ap[2][2];
#pragma unroll
        for (int i = 0; i < 2; i++) {
            const int row = w * 32 + i * 16 + l15;
#pragma unroll
            for (int kk = 0; kk < 2; kk++)
                ap[i][kk] = *(const bf16x8*)&Ps[row * 64 +
                                               (((kk * 4 + quad) ^ (row & 7)) << 3)];
        }
        bf16x8 bv[4][2];
#pragma unroll
        for (int j = 0; j < 4; j++) {
            const int n = j * 16 + l15;
#pragma unroll
            for (int kk = 0; kk < 2; kk++)
                bv[j][kk] = *(const bf16x8*)&Vsub[n * 64 + (((kk * 4 + quad) ^ xk) * 8)];
        }
#pragma unroll
        for (int i = 0; i < 2; i++)
#pragma unroll
            for (int j = 0; j < 4; j++) {
                o[i][j] = MFMA16(ap[i][0], bv[j][0], o[i][j]);
                o[i][j] = MFMA16(ap[i][1], bv[j][1], o[i][j]);
            }
    };

    for (int ktp = 0; ktp < nkA; ktp += 2) {
        // ---- stage two 64-key subtiles (swizzled), one barrier pair ----
#pragma unroll
        for (int sub = 0; sub < 2; ++sub) {
            const int kt = ktp + sub;
            const bf16x8 k0 = *(const bf16x8*)(kgl + kt * 64 * HD + g0 * 8);
            const bf16x8 k1 = *(const bf16x8*)(kgl + kt * 64 * HD + (g0 + 4) * 8);
            const bf16x8 v0 = *(const bf16x8*)(vgl + kt * 64 + g0 * 8);
            const bf16x8 v1 = *(const bf16x8*)(vgl + kt * 64 + (g0 + 4) * 8);
            bf16_t* ks = Ks + sub * 4096 + r_st * 64;
            bf16_t* vs = Vs + sub * 4096 + r_st * 64;
            *(bf16x8*)(ks + sw0) = k0;
            *(bf16x8*)(ks + sw1) = k1;
            *(bf16x8*)(vs + sw0) = v0;
            *(bf16x8*)(vs + sw1) = v1;
        }
        __syncthreads();
#pragma unroll
        for (int sub = 0; sub < 2; ++sub) {
            const int kt = ktp + sub;
            proc(qtA, aqA, oA, liA, kt, sub);
            if (kt < nkB) proc(qtB, aqB, oB, liB, kt, sub);
        }
        __syncthreads();
    }

    // ---- epilogue: reduce li across quads, redistribute, normalize, store --
#pragma unroll
    for (int t = 0; t < 2; t++) {
        const int qt = t == 0 ? qtA : qtB;
        floatx4(&o)[2][4] = t == 0 ? oA : oB;
        float(&li)[2] = t == 0 ? liA : liB;
#pragma unroll
        for (int i = 0; i < 2; i++) {
            float s = li[i];
            s += __shfl_xor(s, 16, 64);
            s += __shfl_xor(s, 32, 64);  // all lanes: total for qrow base+l15
#pragma unroll
            for (int r = 0; r < 4; r++) {
                const float sv = __shfl(s, quad * 4 + r, 64);
                const float inv = 1.0f / sv;
                const int srow = qt * 128 + w * 32 + i * 16 + quad * 4 + r;
                bf16_t* orow = Aout + (size_t)(b * SEQ + srow) * DIM + hd * HD;
#pragma unroll
                for (int j = 0; j < 4; j++)
                    orow[j * 16 + l15] = (bf16_t)(o[i][j][r] * inv);
            }
        }
    }
}

// ---------------------------------------------------------------------------
extern "C" void kernel_launch(void* const* d_in, const int* in_sizes, int n_in,
                              void* d_out, int out_size, void* d_ws, size_t ws_size,
                              hipStream_t stream) {
    const float* x        = (const float*)d_in[0];
    const float* c_attn_w = (const float*)d_in[2];
    const float* c_attn_b = (const float*)d_in[3];
    const float* c_proj_w = (const float*)d_in[4];
    const float* c_proj_b = (const float*)d_in[5];
    float* out = (float*)d_out;

    char* ws = (char*)d_ws;
    bf16_t* xb     = (bf16_t*)ws; ws += (size_t)NB * SEQ * DIM * 2;
    bf16_t* wqkvT  = (bf16_t*)ws; ws += (size_t)3072 * 1024 * 2;
    bf16_t* wprojT = (bf16_t*)ws; ws += (size_t)1024 * 1024 * 2;
    bf16_t* Qb  = (bf16_t*)ws; ws += (size_t)NB * NH * SEQ * HD * 2;
    bf16_t* Kb  = (bf16_t*)ws; ws += (size_t)NB * NH * SEQ * HD * 2;
    bf16_t* Vtb = (bf16_t*)ws; ws += (size_t)NB * NH * SEQ * HD * 2;
    bf16_t* Ab  = (bf16_t*)ws; ws += (size_t)NB * SEQ * DIM * 2;

    prep<<<12288, 256, 0, stream>>>(x, xb, c_attn_w, wqkvT, c_proj_w, wprojT);

    // qkv projection: M=8192, N=3072, K=1024
    gemm128<0><<<dim3(24, 64), 256, 0, stream>>>(xb, wqkvT, c_attn_b, 1024,
                                                 Qb, Kb, Vtb, nullptr);

    // attention: 8 paired q-tile blocks x 64 (b,h) — balanced, all resident
    attn2q<<<dim3(8, NB * NH), 256, 0, stream>>>(Qb, Kb, Vtb, Ab);

    // output projection: M=8192, N=1024, K=1024, fp32 out
    gemm128<1><<<dim3(8, 64), 256, 0, stream>>>(Ab, wprojT, c_proj_b, 1024,
                                                nullptr, nullptr, nullptr, out);
}

// Round 9
// 270.241 us; speedup vs baseline: 2.0592x; 1.0314x over previous
//
#include <hip/hip_runtime.h>

// Problem constants: B=4, S=2048, D=1024, H=16, HD=64
#define SEQ  2048
#define DIM  1024
#define NH   16
#define HD   64
#define NB   4

typedef __bf16 bf16_t;
typedef bf16_t bf16x8 __attribute__((ext_vector_type(8)));
typedef bf16_t bf16x4 __attribute__((ext_vector_type(4)));
typedef float  floatx4 __attribute__((ext_vector_type(4)));

#define MFMA16(a, b, c) __builtin_amdgcn_mfma_f32_16x16x32_bf16((a), (b), (c), 0, 0, 0)

// async global->LDS, 16B per lane (GEMM staging only; LDS dest is wave-uniform
// base + lane*16 — but the GLOBAL source is per-lane, so staged CONTENT can be
// permuted at 16B granularity).
__device__ __forceinline__ void gl_lds16(const bf16_t* g, bf16_t* l) {
    __builtin_amdgcn_global_load_lds(
        (const __attribute__((address_space(1))) void*)g,
        (__attribute__((address_space(3))) void*)l,
        16, 0, 0);
}

// ---------------------------------------------------------------------------
// prep: fused fp32->bf16 convert of x + both weight transposes (one launch)
// ---------------------------------------------------------------------------
__global__ __launch_bounds__(256) void prep(
    const float* __restrict__ x, bf16_t* __restrict__ xb,
    const float* __restrict__ wqkv, bf16_t* __restrict__ wqkvT,
    const float* __restrict__ wproj, bf16_t* __restrict__ wprojT) {
    const int bid = blockIdx.x, tid = threadIdx.x;
    if (bid < 8192) {
        const int i = (bid * 256 + tid) * 4;
        const float4 v = *(const float4*)(x + i);
        xb[i + 0] = (bf16_t)v.x;
        xb[i + 1] = (bf16_t)v.y;
        xb[i + 2] = (bf16_t)v.z;
        xb[i + 3] = (bf16_t)v.w;
        return;
    }
    __shared__ bf16_t t[32][33];
    const float* in;
    bf16_t* out;
    int R, C, bx, by;
    if (bid < 8192 + 3072) {
        const int idx = bid - 8192;
        in = wqkv; out = wqkvT; R = 1024; C = 3072;
        bx = idx % 96; by = idx / 96;
    } else {
        const int idx = bid - 11264;
        in = wproj; out = wprojT; R = 1024; C = 1024;
        bx = idx & 31; by = idx >> 5;
    }
    const int c0 = bx * 32, r0 = by * 32;
    const int tx = tid & 31, ty = tid >> 5;  // 32 x 8
#pragma unroll
    for (int i = 0; i < 32; i += 8)
        t[ty + i][tx] = (bf16_t)in[(r0 + ty + i) * C + c0 + tx];
    __syncthreads();
#pragma unroll
    for (int i = 0; i < 32; i += 8)
        out[(c0 + ty + i) * R + r0 + tx] = t[tx][ty + i];
}

// ---------------------------------------------------------------------------
// GEMM: C[M,N] = A[M,K] * Bt[N,K]^T + bias[n]   (A,Bt bf16; bias fp32)
// K-granule swizzle: granule g of row r is staged at slot s=(g+(r>>1))&3, so
// the b128 fragment read hits 8 bank-groups 2-way per 16-lane phase (was
// 2 groups 8-way — the m98-endemic conflict). Same slot formula for A and B
// keeps the per-(lane,reg) k-mapping identical => MFMA semantics unchanged.
// MODE 0: LDS-staged epilogue -> coalesced 16B stores to
//         Q*0.125 [b,h,s,d], K[b,h,s,d], Vt[b,h,d,s]  (bf16)
// MODE 1: fp32 C row-major (N==1024), direct coalesced stores
// ---------------------------------------------------------------------------
template <int MODE>
__global__ __launch_bounds__(256, 2) void gemm128(
    const bf16_t* __restrict__ A, const bf16_t* __restrict__ Bt,
    const float* __restrict__ bias, int K,
    bf16_t* __restrict__ Qo, bf16_t* __restrict__ Ko, bf16_t* __restrict__ Vo,
    float* __restrict__ Co) {
    __shared__ __align__(16) bf16_t smem[MODE == 0 ? 128 * 136 : 128 * 64];
    bf16_t* Al = smem;
    bf16_t* Bl = smem + 128 * 32;

    const int tid = threadIdx.x;
    const int m0 = blockIdx.y * 128, n0 = blockIdx.x * 128;
    const int w = tid >> 6, lane = tid & 63;
    const int l15 = lane & 15, quad = lane >> 4;
    const int wm = (w & 1) * 64, wn = (w >> 1) * 64;

    floatx4 acc[4][4] = {};

    // staging: thread t fills LDS slot (t&3) of row (t>>2); fetch global
    // granule g = ((t&3) - (t>>3)) & 3  (inverse of s=(g+(r>>1))&3)
    const int g_st = ((tid & 3) - (tid >> 3)) & 3;
    const bf16_t* aptr = A + (m0 + (tid >> 2)) * K + g_st * 8;
    const bf16_t* bptr = Bt + (n0 + (tid >> 2)) * K + g_st * 8;
    bf16_t* al = Al + tid * 8;
    bf16_t* bl = Bl + tid * 8;

    // fragment-read slot (lane-constant, same for A and B)
    const int sAB = ((quad + (l15 >> 1)) & 3) * 8;

    for (int k0 = 0; k0 < K; k0 += 32) {
        gl_lds16(aptr, al);
        gl_lds16(aptr + 64 * K, al + 2048);
        gl_lds16(bptr, bl);
        gl_lds16(bptr + 64 * K, bl + 2048);
        aptr += 32;
        bptr += 32;
        __syncthreads();

        bf16x8 af[4], bfr[4];
#pragma unroll
        for (int i = 0; i < 4; i++)
            af[i] = *(const bf16x8*)&Al[(wm + i * 16 + l15) * 32 + sAB];
#pragma unroll
        for (int j = 0; j < 4; j++)
            bfr[j] = *(const bf16x8*)&Bl[(wn + j * 16 + l15) * 32 + sAB];
#pragma unroll
        for (int i = 0; i < 4; i++)
#pragma unroll
            for (int j = 0; j < 4; j++)
                acc[i][j] = MFMA16(af[i], bfr[j], acc[i][j]);
        __syncthreads();
    }

    if (MODE == 0) {
        bf16_t* Cl = smem;
        const int which = n0 >> 10;  // 0=Q 1=K 2=V, block-uniform
        const float qs = (which == 0) ? 0.125f : 1.0f;
#pragma unroll
        for (int j = 0; j < 4; j++) {
            const int ncol = wn + j * 16 + l15;
            const float bv = bias[n0 + ncol];
#pragma unroll
            for (int i = 0; i < 4; i++)
#pragma unroll
                for (int r = 0; r < 4; r++) {
                    const int mrow = wm + i * 16 + quad * 4 + r;
                    Cl[mrow * 136 + ncol] = (bf16_t)((acc[i][j][r] + bv) * qs);
                }
        }
        __syncthreads();

        if (which < 2) {
            const int row = tid >> 1, ch = (tid & 1) << 6;
            const int m = m0 + row, b = m >> 11, s = m & 2047;
            const int h = ((n0 & 1023) >> 6) + (ch >> 6);
            bf16_t* dst = (which == 0 ? Qo : Ko) + ((size_t)(b * NH + h) * SEQ + s) * HD;
            const bf16_t* src = Cl + row * 136 + ch;
#pragma unroll
            for (int g = 0; g < 8; g++)
                *(bf16x8*)(dst + g * 8) = *(const bf16x8*)(src + g * 8);
        } else {
            const int dl = tid & 127, sh = (tid >> 7) << 6;
            const int h = ((n0 & 1023) >> 6) + (dl >> 6), d = dl & 63;
            const int b = m0 >> 11, sbase = (m0 & 2047) + sh;
            bf16_t* dst = Vo + ((size_t)(b * NH + h) * HD + d) * SEQ + sbase;
#pragma unroll
            for (int g = 0; g < 8; g++) {
                bf16x8 tv;
#pragma unroll
                for (int e = 0; e < 8; e++)
                    tv[e] = Cl[(sh + g * 8 + e) * 136 + dl];
                *(bf16x8*)(dst + g * 8) = tv;
            }
        }
    } else {
#pragma unroll
        for (int j = 0; j < 4; j++) {
            const int n = n0 + wn + j * 16 + l15;
            const float bv = bias[n];
#pragma unroll
            for (int i = 0; i < 4; i++)
#pragma unroll
                for (int r = 0; r < 4; r++) {
                    const int m = m0 + wm + i * 16 + quad * 4 + r;
                    Co[m * 1024 + n] = acc[i][j][r] + bv;
                }
        }
    }
}

// ---------------------------------------------------------------------------
// Flash attention, causal, no-running-max. Two q-tiles/block (qtA=15-px long,
// qtB=px short) share each staged K/V tile; 128 keys staged per barrier pair.
// S^T = K*Q^T -> packed b64 P-stores, scalar per-lane row-sums. Ps wave-
// private: lgkmcnt(0) wait, no barrier. (256,2) only — round-5 spill lesson.
// ---------------------------------------------------------------------------
__global__ __launch_bounds__(256, 2) void attn2q(
    const bf16_t* __restrict__ Q, const bf16_t* __restrict__ Kg,
    const bf16_t* __restrict__ Vt, bf16_t* __restrict__ Aout) {
    __shared__ bf16_t Ks[2 * 64 * 64];  // [sub][key][d], granule-swizzled
    __shared__ bf16_t Vs[2 * 64 * 64];  // [sub][d][key], granule-swizzled
    __shared__ bf16_t Ps[128 * 64];     // [qrow][key],   granule-swizzled

    const int bh = blockIdx.y;
    const int px = (blockIdx.x + (bh >> 3)) & 7;  // scramble so CU-mates differ
    const int qtA = 15 - px, qtB = px;
    const int nkA = 2 * qtA + 2, nkB = 2 * qtB + 2;  // both even

    const int tid = threadIdx.x, w = tid >> 6, lane = tid & 63;
    const int l15 = lane & 15, quad = lane >> 4;
    const int b = bh >> 4, hd = bh & 15;
    const int xk = l15 & 7;

    // Q fragments for both tiles (B-operand of S^T = K Q^T)
    bf16x8 aqA[2][2], aqB[2][2];
#pragma unroll
    for (int i = 0; i < 2; i++) {
        const bf16_t* qrA = Q + (size_t)(bh * SEQ + qtA * 128 + w * 32 + i * 16 + l15) * HD;
        const bf16_t* qrB = Q + (size_t)(bh * SEQ + qtB * 128 + w * 32 + i * 16 + l15) * HD;
#pragma unroll
        for (int h = 0; h < 2; h++) {
            aqA[i][h] = *(const bf16x8*)(qrA + h * 32 + quad * 8);
            aqB[i][h] = *(const bf16x8*)(qrB + h * 32 + quad * 8);
        }
    }

    floatx4 oA[2][4] = {}, oB[2][4] = {};
    float liA[2] = {}, liB[2] = {};

    // staging: thread t -> subtile row t>>2, granules (t&3), (t&3)+4
    const int r_st = tid >> 2, g0 = tid & 3;
    const bf16_t* kgl = Kg + (size_t)bh * SEQ * HD + (size_t)r_st * HD;
    const bf16_t* vgl = Vt + (size_t)bh * HD * SEQ + (size_t)r_st * SEQ;
    const int sw0 = ((g0 ^ (r_st & 7)) * 8);
    const int sw1 = (((g0 + 4) ^ (r_st & 7)) * 8);

    auto proc = [&](int qt, bf16x8 (&aq)[2][2], floatx4 (&o)[2][4],
                    float (&li)[2], int kt, int sub) {
        const bf16_t* Ksub = Ks + sub * 4096;
        const bf16_t* Vsub = Vs + sub * 4096;
        // S^T = K Q^T : C col = qrow (l15), row = key (quad*4+r)
        bf16x8 bk[4][2];
#pragma unroll
        for (int j = 0; j < 4; j++) {
            const int n = j * 16 + l15;
#pragma unroll
            for (int h = 0; h < 2; h++)
                bk[j][h] = *(const bf16x8*)&Ksub[n * 64 + (((h * 4 + quad) ^ xk) * 8)];
        }
        floatx4 z[2][4] = {};
#pragma unroll
        for (int i = 0; i < 2; i++)
#pragma unroll
            for (int j = 0; j < 4; j++) {
                z[i][j] = MFMA16(bk[j][0], aq[i][0], z[i][j]);
                z[i][j] = MFMA16(bk[j][1], aq[i][1], z[i][j]);
            }
        // exp + causal mask + per-lane row-sum + packed b64 P-store
#pragma unroll
        for (int i = 0; i < 2; i++) {
            const int qbase = qt * 128 + w * 32 + i * 16;
            const int qrow_l = qbase + l15;
            const bool full = (kt * 64 + 63) <= qbase;
            const int prow = w * 32 + i * 16 + l15;
            bf16_t* pbase = Ps + prow * 64;
            const int rx = prow & 7;
#pragma unroll
            for (int j = 0; j < 4; j++) {
                const int kg0 = kt * 64 + j * 16 + quad * 4;
                bf16x4 pk;
#pragma unroll
                for (int r = 0; r < 4; r++) {
                    float e = __expf(z[i][j][r]);
                    if (!full && kg0 + r > qrow_l) e = 0.f;
                    li[i] += e;
                    pk[r] = (bf16_t)e;
                }
                const int g = 2 * j + (quad >> 1);
                *(bf16x4*)(pbase + (((g ^ rx) << 3) | ((quad & 1) << 2))) = pk;
            }
        }
        __builtin_amdgcn_s_waitcnt(0xC07F);  // lgkmcnt(0); Ps is wave-private
        // O += P V
        bf16x8 ap[2][2];
#pragma unroll
        for (int i = 0; i < 2; i++) {
            const int row = w * 32 + i * 16 + l15;
#pragma unroll
            for (int kk = 0; kk < 2; kk++)
                ap[i][kk] = *(const bf16x8*)&Ps[row * 64 +
                                               (((kk * 4 + quad) ^ (row & 7)) << 3)];
        }
        bf16x8 bv[4][2];
#pragma unroll
        for (int j = 0; j < 4; j++) {
            const int n = j * 16 + l15;
#pragma unroll
            for (int kk = 0; kk < 2; kk++)
                bv[j][kk] = *(const bf16x8*)&Vsub[n * 64 + (((kk * 4 + quad) ^ xk) * 8)];
        }
#pragma unroll
        for (int i = 0; i < 2; i++)
#pragma unroll
            for (int j = 0; j < 4; j++) {
                o[i][j] = MFMA16(ap[i][0], bv[j][0], o[i][j]);
                o[i][j] = MFMA16(ap[i][1], bv[j][1], o[i][j]);
            }
    };

    for (int ktp = 0; ktp < nkA; ktp += 2) {
        // ---- stage two 64-key subtiles (swizzled), one barrier pair ----
#pragma unroll
        for (int sub = 0; sub < 2; ++sub) {
            const int kt = ktp + sub;
            const bf16x8 k0 = *(const bf16x8*)(kgl + kt * 64 * HD + g0 * 8);
            const bf16x8 k1 = *(const bf16x8*)(kgl + kt * 64 * HD + (g0 + 4) * 8);
            const bf16x8 v0 = *(const bf16x8*)(vgl + kt * 64 + g0 * 8);
            const bf16x8 v1 = *(const bf16x8*)(vgl + kt * 64 + (g0 + 4) * 8);
            bf16_t* ks = Ks + sub * 4096 + r_st * 64;
            bf16_t* vs = Vs + sub * 4096 + r_st * 64;
            *(bf16x8*)(ks + sw0) = k0;
            *(bf16x8*)(ks + sw1) = k1;
            *(bf16x8*)(vs + sw0) = v0;
            *(bf16x8*)(vs + sw1) = v1;
        }
        __syncthreads();
#pragma unroll
        for (int sub = 0; sub < 2; ++sub) {
            const int kt = ktp + sub;
            proc(qtA, aqA, oA, liA, kt, sub);
            if (kt < nkB) proc(qtB, aqB, oB, liB, kt, sub);
        }
        __syncthreads();
    }

    // ---- epilogue: reduce li across quads, redistribute, normalize, store --
#pragma unroll
    for (int t = 0; t < 2; t++) {
        const int qt = t == 0 ? qtA : qtB;
        floatx4(&o)[2][4] = t == 0 ? oA : oB;
        float(&li)[2] = t == 0 ? liA : liB;
#pragma unroll
        for (int i = 0; i < 2; i++) {
            float s = li[i];
            s += __shfl_xor(s, 16, 64);
            s += __shfl_xor(s, 32, 64);  // all lanes: total for qrow base+l15
#pragma unroll
            for (int r = 0; r < 4; r++) {
                const float sv = __shfl(s, quad * 4 + r, 64);
                const float inv = 1.0f / sv;
                const int srow = qt * 128 + w * 32 + i * 16 + quad * 4 + r;
                bf16_t* orow = Aout + (size_t)(b * SEQ + srow) * DIM + hd * HD;
#pragma unroll
                for (int j = 0; j < 4; j++)
                    orow[j * 16 + l15] = (bf16_t)(o[i][j][r] * inv);
            }
        }
    }
}

// ---------------------------------------------------------------------------
extern "C" void kernel_launch(void* const* d_in, const int* in_sizes, int n_in,
                              void* d_out, int out_size, void* d_ws, size_t ws_size,
                              hipStream_t stream) {
    const float* x        = (const float*)d_in[0];
    const float* c_attn_w = (const float*)d_in[2];
    const float* c_attn_b = (const float*)d_in[3];
    const float* c_proj_w = (const float*)d_in[4];
    const float* c_proj_b = (const float*)d_in[5];
    float* out = (float*)d_out;

    char* ws = (char*)d_ws;
    bf16_t* xb     = (bf16_t*)ws; ws += (size_t)NB * SEQ * DIM * 2;
    bf16_t* wqkvT  = (bf16_t*)ws; ws += (size_t)3072 * 1024 * 2;
    bf16_t* wprojT = (bf16_t*)ws; ws += (size_t)1024 * 1024 * 2;
    bf16_t* Qb  = (bf16_t*)ws; ws += (size_t)NB * NH * SEQ * HD * 2;
    bf16_t* Kb  = (bf16_t*)ws; ws += (size_t)NB * NH * SEQ * HD * 2;
    bf16_t* Vtb = (bf16_t*)ws; ws += (size_t)NB * NH * SEQ * HD * 2;
    bf16_t* Ab  = (bf16_t*)ws; ws += (size_t)NB * SEQ * DIM * 2;

    prep<<<12288, 256, 0, stream>>>(x, xb, c_attn_w, wqkvT, c_proj_w, wprojT);

    // qkv projection: M=8192, N=3072, K=1024
    gemm128<0><<<dim3(24, 64), 256, 0, stream>>>(xb, wqkvT, c_attn_b, 1024,
                                                 Qb, Kb, Vtb, nullptr);

    // attention: 8 paired q-tile blocks x 64 (b,h) — balanced, all resident
    attn2q<<<dim3(8, NB * NH), 256, 0, stream>>>(Qb, Kb, Vtb, Ab);

    // output projection: M=8192, N=1024, K=1024, fp32 out
    gemm128<1><<<dim3(8, 64), 256, 0, stream>>>(Ab, wprojT, c_proj_b, 1024,
                                                nullptr, nullptr, nullptr, out);
}

// Round 10
// 256.032 us; speedup vs baseline: 2.1735x; 1.0555x over previous
//
#include <hip/hip_runtime.h>

// Problem constants: B=4, S=2048, D=1024, H=16, HD=64
#define SEQ  2048
#define DIM  1024
#define NH   16
#define HD   64
#define NB   4

typedef __bf16 bf16_t;
typedef bf16_t bf16x8 __attribute__((ext_vector_type(8)));
typedef bf16_t bf16x4 __attribute__((ext_vector_type(4)));
typedef float  floatx4 __attribute__((ext_vector_type(4)));

#define MFMA16(a, b, c) __builtin_amdgcn_mfma_f32_16x16x32_bf16((a), (b), (c), 0, 0, 0)

// async global->LDS, 16B per lane (GEMM staging only; LDS dest is wave-uniform
// base + lane*16 — but the GLOBAL source is per-lane, so staged CONTENT can be
// permuted at 16B granularity).
__device__ __forceinline__ void gl_lds16(const bf16_t* g, bf16_t* l) {
    __builtin_amdgcn_global_load_lds(
        (const __attribute__((address_space(1))) void*)g,
        (__attribute__((address_space(3))) void*)l,
        16, 0, 0);
}

// ---------------------------------------------------------------------------
// prep: fused fp32->bf16 convert of x + both weight transposes (one launch)
// ---------------------------------------------------------------------------
__global__ __launch_bounds__(256) void prep(
    const float* __restrict__ x, bf16_t* __restrict__ xb,
    const float* __restrict__ wqkv, bf16_t* __restrict__ wqkvT,
    const float* __restrict__ wproj, bf16_t* __restrict__ wprojT) {
    const int bid = blockIdx.x, tid = threadIdx.x;
    if (bid < 8192) {
        const int i = (bid * 256 + tid) * 4;
        const float4 v = *(const float4*)(x + i);
        xb[i + 0] = (bf16_t)v.x;
        xb[i + 1] = (bf16_t)v.y;
        xb[i + 2] = (bf16_t)v.z;
        xb[i + 3] = (bf16_t)v.w;
        return;
    }
    __shared__ bf16_t t[32][33];
    const float* in;
    bf16_t* out;
    int R, C, bx, by;
    if (bid < 8192 + 3072) {
        const int idx = bid - 8192;
        in = wqkv; out = wqkvT; R = 1024; C = 3072;
        bx = idx % 96; by = idx / 96;
    } else {
        const int idx = bid - 11264;
        in = wproj; out = wprojT; R = 1024; C = 1024;
        bx = idx & 31; by = idx >> 5;
    }
    const int c0 = bx * 32, r0 = by * 32;
    const int tx = tid & 31, ty = tid >> 5;  // 32 x 8
#pragma unroll
    for (int i = 0; i < 32; i += 8)
        t[ty + i][tx] = (bf16_t)in[(r0 + ty + i) * C + c0 + tx];
    __syncthreads();
#pragma unroll
    for (int i = 0; i < 32; i += 8)
        out[(c0 + ty + i) * R + r0 + tx] = t[tx][ty + i];
}

// ---------------------------------------------------------------------------
// GEMM: C[M,N] = A[M,K] * Bt[N,K]^T + bias[n]   (A,Bt bf16; bias fp32)
// BK=64: 32 MFMAs per barrier pair (was 16) — halves the structural
// vmcnt(0)/lgkmcnt(0) barrier-drain count; LDS stays 34 KB (MODE 0 epilogue
// tile already reserved that), occupancy unchanged.  8-slot K-granule
// swizzle: slot s=(g+row)&7, read slot=(h*4+quad+l15)&7 -> 2-way (free).
// MODE 0 computes C^T (swapped MFMA operands, attn round-8 pattern): lane
// holds 4 consecutive n-cols of one m-row -> packed b64 LDS epilogue writes.
// MODE 0: LDS-staged epilogue -> coalesced 16B stores to
//         Q*0.125 [b,h,s,d], K[b,h,s,d], Vt[b,h,d,s]  (bf16)
// MODE 1: fp32 C row-major (N==1024), direct coalesced stores (unswapped)
// ---------------------------------------------------------------------------
template <int MODE>
__global__ __launch_bounds__(256, 2) void gemm128(
    const bf16_t* __restrict__ A, const bf16_t* __restrict__ Bt,
    const float* __restrict__ bias, int K,
    bf16_t* __restrict__ Qo, bf16_t* __restrict__ Ko, bf16_t* __restrict__ Vo,
    float* __restrict__ Co) {
    // staging Al/Bl 128x64 each (32 KB); MODE 0 epilogue reuses as 128x136 tile
    __shared__ __align__(16) bf16_t smem[MODE == 0 ? 128 * 136 : 128 * 128];
    bf16_t* Al = smem;
    bf16_t* Bl = smem + 128 * 64;

    const int tid = threadIdx.x;
    const int m0 = blockIdx.y * 128, n0 = blockIdx.x * 128;
    const int w = tid >> 6, lane = tid & 63;
    const int l15 = lane & 15, quad = lane >> 4;
    const int wm = (w & 1) * 64, wn = (w >> 1) * 64;

    floatx4 acc[4][4] = {};

    // staging: thread t fills LDS slot (t&7) of row (t>>3)+c*32, c=0..3;
    // fetch global granule g = ((t&7)-(t>>3)) & 7  (inverse of s=(g+row)&7;
    // c*32 = 0 mod 8 so one formula serves all four chunks)
    const int g_st = ((tid & 7) - (tid >> 3)) & 7;
    const bf16_t* aptr = A + (m0 + (tid >> 3)) * K + g_st * 8;
    const bf16_t* bptr = Bt + (n0 + (tid >> 3)) * K + g_st * 8;
    bf16_t* al = Al + tid * 8;
    bf16_t* bl = Bl + tid * 8;

    for (int k0 = 0; k0 < K; k0 += 64) {
#pragma unroll
        for (int c = 0; c < 4; c++) {
            gl_lds16(aptr + (c * 32) * K, al + c * 2048);
            gl_lds16(bptr + (c * 32) * K, bl + c * 2048);
        }
        aptr += 64;
        bptr += 64;
        __syncthreads();

#pragma unroll
        for (int h = 0; h < 2; h++) {
            const int sAB = (((h << 2) + quad + (l15 & 7)) & 7) * 8;
            bf16x8 af[4], bfr[4];
#pragma unroll
            for (int i = 0; i < 4; i++)
                af[i] = *(const bf16x8*)&Al[(wm + i * 16 + l15) * 64 + sAB];
#pragma unroll
            for (int j = 0; j < 4; j++)
                bfr[j] = *(const bf16x8*)&Bl[(wn + j * 16 + l15) * 64 + sAB];
#pragma unroll
            for (int i = 0; i < 4; i++)
#pragma unroll
                for (int j = 0; j < 4; j++)
                    acc[i][j] = MODE == 0 ? MFMA16(bfr[j], af[i], acc[i][j])
                                          : MFMA16(af[i], bfr[j], acc[i][j]);
        }
        __syncthreads();
    }

    if (MODE == 0) {
        // C^T layout: row m = wm+i*16+l15 (lane-fixed), col n = wn+j*16+quad*4+r
        bf16_t* Cl = smem;
        const int which = n0 >> 10;  // 0=Q 1=K 2=V, block-uniform
        const float qs = (which == 0) ? 0.125f : 1.0f;
#pragma unroll
        for (int j = 0; j < 4; j++) {
            const int nc = wn + j * 16 + quad * 4;
#pragma unroll
            for (int i = 0; i < 4; i++) {
                const int mrow = wm + i * 16 + l15;
                bf16x4 pk;
#pragma unroll
                for (int r = 0; r < 4; r++)
                    pk[r] = (bf16_t)((acc[i][j][r] + bias[n0 + nc + r]) * qs);
                *(bf16x4*)&Cl[mrow * 136 + nc] = pk;
            }
        }
        __syncthreads();

        if (which < 2) {
            const int row = tid >> 1, ch = (tid & 1) << 6;
            const int m = m0 + row, b = m >> 11, s = m & 2047;
            const int h = ((n0 & 1023) >> 6) + (ch >> 6);
            bf16_t* dst = (which == 0 ? Qo : Ko) + ((size_t)(b * NH + h) * SEQ + s) * HD;
            const bf16_t* src = Cl + row * 136 + ch;
#pragma unroll
            for (int g = 0; g < 8; g++)
                *(bf16x8*)(dst + g * 8) = *(const bf16x8*)(src + g * 8);
        } else {
            const int dl = tid & 127, sh = (tid >> 7) << 6;
            const int h = ((n0 & 1023) >> 6) + (dl >> 6), d = dl & 63;
            const int b = m0 >> 11, sbase = (m0 & 2047) + sh;
            bf16_t* dst = Vo + ((size_t)(b * NH + h) * HD + d) * SEQ + sbase;
#pragma unroll
            for (int g = 0; g < 8; g++) {
                bf16x8 tv;
#pragma unroll
                for (int e = 0; e < 8; e++)
                    tv[e] = Cl[(sh + g * 8 + e) * 136 + dl];
                *(bf16x8*)(dst + g * 8) = tv;
            }
        }
    } else {
        // unswapped C: row m = wm+i*16+quad*4+r, col n = wn+j*16+l15 (coalesced)
#pragma unroll
        for (int j = 0; j < 4; j++) {
            const int n = n0 + wn + j * 16 + l15;
            const float bv = bias[n];
#pragma unroll
            for (int i = 0; i < 4; i++)
#pragma unroll
                for (int r = 0; r < 4; r++) {
                    const int m = m0 + wm + i * 16 + quad * 4 + r;
                    Co[m * 1024 + n] = acc[i][j][r] + bv;
                }
        }
    }
}

// ---------------------------------------------------------------------------
// Flash attention, causal, no-running-max. Two q-tiles/block (qtA=15-px long,
// qtB=px short) share each staged K/V tile; 128 keys staged per barrier pair.
// S^T = K*Q^T -> packed b64 P-stores, scalar per-lane row-sums. Ps wave-
// private: lgkmcnt(0) wait, no barrier. (256,2) only — round-5 spill lesson.
// ---------------------------------------------------------------------------
__global__ __launch_bounds__(256, 2) void attn2q(
    const bf16_t* __restrict__ Q, const bf16_t* __restrict__ Kg,
    const bf16_t* __restrict__ Vt, bf16_t* __restrict__ Aout) {
    __shared__ bf16_t Ks[2 * 64 * 64];  // [sub][key][d], granule-swizzled
    __shared__ bf16_t Vs[2 * 64 * 64];  // [sub][d][key], granule-swizzled
    __shared__ bf16_t Ps[128 * 64];     // [qrow][key],   granule-swizzled

    const int bh = blockIdx.y;
    const int px = (blockIdx.x + (bh >> 3)) & 7;  // scramble so CU-mates differ
    const int qtA = 15 - px, qtB = px;
    const int nkA = 2 * qtA + 2, nkB = 2 * qtB + 2;  // both even

    const int tid = threadIdx.x, w = tid >> 6, lane = tid & 63;
    const int l15 = lane & 15, quad = lane >> 4;
    const int b = bh >> 4, hd = bh & 15;
    const int xk = l15 & 7;

    // Q fragments for both tiles (B-operand of S^T = K Q^T)
    bf16x8 aqA[2][2], aqB[2][2];
#pragma unroll
    for (int i = 0; i < 2; i++) {
        const bf16_t* qrA = Q + (size_t)(bh * SEQ + qtA * 128 + w * 32 + i * 16 + l15) * HD;
        const bf16_t* qrB = Q + (size_t)(bh * SEQ + qtB * 128 + w * 32 + i * 16 + l15) * HD;
#pragma unroll
        for (int h = 0; h < 2; h++) {
            aqA[i][h] = *(const bf16x8*)(qrA + h * 32 + quad * 8);
            aqB[i][h] = *(const bf16x8*)(qrB + h * 32 + quad * 8);
        }
    }

    floatx4 oA[2][4] = {}, oB[2][4] = {};
    float liA[2] = {}, liB[2] = {};

    // staging: thread t -> subtile row t>>2, granules (t&3), (t&3)+4
    const int r_st = tid >> 2, g0 = tid & 3;
    const bf16_t* kgl = Kg + (size_t)bh * SEQ * HD + (size_t)r_st * HD;
    const bf16_t* vgl = Vt + (size_t)bh * HD * SEQ + (size_t)r_st * SEQ;
    const int sw0 = ((g0 ^ (r_st & 7)) * 8);
    const int sw1 = (((g0 + 4) ^ (r_st & 7)) * 8);

    auto proc = [&](int qt, bf16x8 (&aq)[2][2], floatx4 (&o)[2][4],
                    float (&li)[2], int kt, int sub) {
        const bf16_t* Ksub = Ks + sub * 4096;
        const bf16_t* Vsub = Vs + sub * 4096;
        // S^T = K Q^T : C col = qrow (l15), row = key (quad*4+r)
        bf16x8 bk[4][2];
#pragma unroll
        for (int j = 0; j < 4; j++) {
            const int n = j * 16 + l15;
#pragma unroll
            for (int h = 0; h < 2; h++)
                bk[j][h] = *(const bf16x8*)&Ksub[n * 64 + (((h * 4 + quad) ^ xk) * 8)];
        }
        floatx4 z[2][4] = {};
#pragma unroll
        for (int i = 0; i < 2; i++)
#pragma unroll
            for (int j = 0; j < 4; j++) {
                z[i][j] = MFMA16(bk[j][0], aq[i][0], z[i][j]);
                z[i][j] = MFMA16(bk[j][1], aq[i][1], z[i][j]);
            }
        // exp + causal mask + per-lane row-sum + packed b64 P-store
#pragma unroll
        for (int i = 0; i < 2; i++) {
            const int qbase = qt * 128 + w * 32 + i * 16;
            const int qrow_l = qbase + l15;
            const bool full = (kt * 64 + 63) <= qbase;
            const int prow = w * 32 + i * 16 + l15;
            bf16_t* pbase = Ps + prow * 64;
            const int rx = prow & 7;
#pragma unroll
            for (int j = 0; j < 4; j++) {
                const int kg0 = kt * 64 + j * 16 + quad * 4;
                bf16x4 pk;
#pragma unroll
                for (int r = 0; r < 4; r++) {
                    float e = __expf(z[i][j][r]);
                    if (!full && kg0 + r > qrow_l) e = 0.f;
                    li[i] += e;
                    pk[r] = (bf16_t)e;
                }
                const int g = 2 * j + (quad >> 1);
                *(bf16x4*)(pbase + (((g ^ rx) << 3) | ((quad & 1) << 2))) = pk;
            }
        }
        __builtin_amdgcn_s_waitcnt(0xC07F);  // lgkmcnt(0); Ps is wave-private
        // O += P V
        bf16x8 ap[2][2];
#pragma unroll
        for (int i = 0; i < 2; i++) {
            const int row = w * 32 + i * 16 + l15;
#pragma unroll
            for (int kk = 0; kk < 2; kk++)
                ap[i][kk] = *(const bf16x8*)&Ps[row * 64 +
                                               (((kk * 4 + quad) ^ (row & 7)) << 3)];
        }
        bf16x8 bv[4][2];
#pragma unroll
        for (int j = 0; j < 4; j++) {
            const int n = j * 16 + l15;
#pragma unroll
            for (int kk = 0; kk < 2; kk++)
                bv[j][kk] = *(const bf16x8*)&Vsub[n * 64 + (((kk * 4 + quad) ^ xk) * 8)];
        }
#pragma unroll
        for (int i = 0; i < 2; i++)
#pragma unroll
            for (int j = 0; j < 4; j++) {
                o[i][j] = MFMA16(ap[i][0], bv[j][0], o[i][j]);
                o[i][j] = MFMA16(ap[i][1], bv[j][1], o[i][j]);
            }
    };

    for (int ktp = 0; ktp < nkA; ktp += 2) {
        // ---- stage two 64-key subtiles (swizzled), one barrier pair ----
#pragma unroll
        for (int sub = 0; sub < 2; ++sub) {
            const int kt = ktp + sub;
            const bf16x8 k0 = *(const bf16x8*)(kgl + kt * 64 * HD + g0 * 8);
            const bf16x8 k1 = *(const bf16x8*)(kgl + kt * 64 * HD + (g0 + 4) * 8);
            const bf16x8 v0 = *(const bf16x8*)(vgl + kt * 64 + g0 * 8);
            const bf16x8 v1 = *(const bf16x8*)(vgl + kt * 64 + (g0 + 4) * 8);
            bf16_t* ks = Ks + sub * 4096 + r_st * 64;
            bf16_t* vs = Vs + sub * 4096 + r_st * 64;
            *(bf16x8*)(ks + sw0) = k0;
            *(bf16x8*)(ks + sw1) = k1;
            *(bf16x8*)(vs + sw0) = v0;
            *(bf16x8*)(vs + sw1) = v1;
        }
        __syncthreads();
#pragma unroll
        for (int sub = 0; sub < 2; ++sub) {
            const int kt = ktp + sub;
            proc(qtA, aqA, oA, liA, kt, sub);
            if (kt < nkB) proc(qtB, aqB, oB, liB, kt, sub);
        }
        __syncthreads();
    }

    // ---- epilogue: reduce li across quads, redistribute, normalize, store --
#pragma unroll
    for (int t = 0; t < 2; t++) {
        const int qt = t == 0 ? qtA : qtB;
        floatx4(&o)[2][4] = t == 0 ? oA : oB;
        float(&li)[2] = t == 0 ? liA : liB;
#pragma unroll
        for (int i = 0; i < 2; i++) {
            float s = li[i];
            s += __shfl_xor(s, 16, 64);
            s += __shfl_xor(s, 32, 64);  // all lanes: total for qrow base+l15
#pragma unroll
            for (int r = 0; r < 4; r++) {
                const float sv = __shfl(s, quad * 4 + r, 64);
                const float inv = 1.0f / sv;
                const int srow = qt * 128 + w * 32 + i * 16 + quad * 4 + r;
                bf16_t* orow = Aout + (size_t)(b * SEQ + srow) * DIM + hd * HD;
#pragma unroll
                for (int j = 0; j < 4; j++)
                    orow[j * 16 + l15] = (bf16_t)(o[i][j][r] * inv);
            }
        }
    }
}

// ---------------------------------------------------------------------------
extern "C" void kernel_launch(void* const* d_in, const int* in_sizes, int n_in,
                              void* d_out, int out_size, void* d_ws, size_t ws_size,
                              hipStream_t stream) {
    const float* x        = (const float*)d_in[0];
    const float* c_attn_w = (const float*)d_in[2];
    const float* c_attn_b = (const float*)d_in[3];
    const float* c_proj_w = (const float*)d_in[4];
    const float* c_proj_b = (const float*)d_in[5];
    float* out = (float*)d_out;

    char* ws = (char*)d_ws;
    bf16_t* xb     = (bf16_t*)ws; ws += (size_t)NB * SEQ * DIM * 2;
    bf16_t* wqkvT  = (bf16_t*)ws; ws += (size_t)3072 * 1024 * 2;
    bf16_t* wprojT = (bf16_t*)ws; ws += (size_t)1024 * 1024 * 2;
    bf16_t* Qb  = (bf16_t*)ws; ws += (size_t)NB * NH * SEQ * HD * 2;
    bf16_t* Kb  = (bf16_t*)ws; ws += (size_t)NB * NH * SEQ * HD * 2;
    bf16_t* Vtb = (bf16_t*)ws; ws += (size_t)NB * NH * SEQ * HD * 2;
    bf16_t* Ab  = (bf16_t*)ws; ws += (size_t)NB * SEQ * DIM * 2;

    prep<<<12288, 256, 0, stream>>>(x, xb, c_attn_w, wqkvT, c_proj_w, wprojT);

    // qkv projection: M=8192, N=3072, K=1024
    gemm128<0><<<dim3(24, 64), 256, 0, stream>>>(xb, wqkvT, c_attn_b, 1024,
                                                 Qb, Kb, Vtb, nullptr);

    // attention: 8 paired q-tile blocks x 64 (b,h) — balanced, all resident
    attn2q<<<dim3(8, NB * NH), 256, 0, stream>>>(Qb, Kb, Vtb, Ab);

    // output projection: M=8192, N=1024, K=1024, fp32 out
    gemm128<1><<<dim3(8, 64), 256, 0, stream>>>(Ab, wprojT, c_proj_b, 1024,
                                                nullptr, nullptr, nullptr, out);
}